// Round 15
// baseline (180.620 us; speedup 1.0000x reference)
//
#include <hip/hip_runtime.h>
#include <math.h>

#define NT 256

typedef __attribute__((ext_vector_type(4))) float  f32x4;
typedef __attribute__((ext_vector_type(8))) short  bf16x8;
typedef __attribute__((ext_vector_type(4))) short  bf16x4;

static __device__ __forceinline__ short f2bf(float f) {
    unsigned u = __builtin_bit_cast(unsigned, f);
    unsigned r = (u + 0x7fffu + ((u >> 16) & 1u)) >> 16;
    return (short)r;
}

// round-to-nearest-even bf16 pair-pack, pure VALU (no asm, no union)
static __device__ __forceinline__ unsigned pk2(float a, float b) {
    unsigned ua = __builtin_bit_cast(unsigned, a);
    unsigned ub = __builtin_bit_cast(unsigned, b);
    ua = (ua + 0x7fffu + ((ua >> 16) & 1u)) >> 16;
    ub = (ub + 0x7fffu + ((ub >> 16) & 1u)) & 0xffff0000u;
    return ua | ub;
}
static __device__ __forceinline__ bf16x4 pk_bf16(f32x4 d) {
    uint2 t;
    t.x = pk2(d[0], d[1]);
    t.y = pk2(d[2], d[3]);
    return __builtin_bit_cast(bf16x4, t);
}
static __device__ __forceinline__ bf16x8 pk_bf16x8(f32x4 a, f32x4 b) {
    uint4 t;
    t.x = pk2(a[0], a[1]);
    t.y = pk2(a[2], a[3]);
    t.z = pk2(b[0], b[1]);
    t.w = pk2(b[2], b[3]);
    return __builtin_bit_cast(bf16x8, t);
}
static __device__ __forceinline__ bf16x8 cat44(bf16x4 a, bf16x4 b) {
    return __builtin_shufflevector(a, b, 0, 1, 2, 3, 4, 5, 6, 7);
}

#define MFMA16x32(a, b, c) __builtin_amdgcn_mfma_f32_16x16x32_bf16(a, b, c, 0, 0, 0)

#if __has_builtin(__builtin_amdgcn_mfma_f32_16x16x16bf16_1k)
static __device__ __forceinline__ f32x4 mfma16x16(bf16x4 a, bf16x4 b, f32x4 c) {
    return __builtin_amdgcn_mfma_f32_16x16x16bf16_1k(a, b, c, 0, 0, 0);
}
#elif __has_builtin(__builtin_amdgcn_mfma_f32_16x16x16_bf16)
static __device__ __forceinline__ f32x4 mfma16x16(bf16x4 a, bf16x4 b, f32x4 c) {
    return __builtin_amdgcn_mfma_f32_16x16x16_bf16(a, b, c, 0, 0, 0);
}
#else
static __device__ __forceinline__ f32x4 mfma16x16(bf16x4 a, bf16x4 b, f32x4 c) {
    f32x4 d;
    asm("v_mfma_f32_16x16x16_bf16 %0, %1, %2, %3" : "=v"(d) : "v"(a), "v"(b), "v"(c));
    return d;
}
#endif

// ws layout (units: unsigned short):
// WS_FPK: packed FFN weights, chunk-major, [2 layers][32 chunks][8192]:
//   A(2048)=W1 cols 0..31 frag-order, B(2048)=W1 cols 32..63,
//   C(2048)=W2 nf0/1 PAIRED layout, D(2048)=W2 nf2/3 PAIRED layout.
#define WS_FPK  0           // (524288)
#define WS_QKV  524288      // in_proj_w [2][192][64]  (24576)
#define WS_WO   548864      // out_w [2][64][64]       (8192)
#define WS_BASE 557056
#define WS_MW1  557056      // mlp_w1 padded [128][64] (8192)
#define WS_MW2  565248      // mlp_w2 [64][128]        (8192)
#define WS_TOTAL 573440

// ---------------------------------------------------------------------------
// Kernel 0: convert + pack weights to bf16 in d_ws (unchanged from R13)
// ---------------------------------------------------------------------------
__global__ __launch_bounds__(NT) void k_cvtw(
    const float* __restrict__ ffn_w1, const float* __restrict__ ffn_w2,
    const float* __restrict__ in_proj_w, const float* __restrict__ out_w,
    const float* __restrict__ mlp_w1, const float* __restrict__ mlp_w2,
    int do_mlp,
    unsigned short* __restrict__ ws)
{
    int i = blockIdx.x * NT + threadIdx.x;
    if (i < 524288) {
        int l = i >> 18;
        int w = i & 262143;
        int c = w >> 13;
        int ww = w & 8191;
        int region = ww >> 11;
        int q = ww & 2047;
        const float* W1 = ffn_w1 + l * 131072;   // [2048][64]
        const float* W2 = ffn_w2 + l * 131072;   // [64][2048]
        float v;
        if (region <= 1) {
            int lane = q >> 3, j = q & 7;
            int lg = (lane >> 4) & 3, lr = lane & 15;
            int hc = lane >> 6;
            v = W1[(c * 64 + hc * 16 + lr) * 64 + region * 32 + lg * 8 + j];
        } else {
            int sub = q >> 9;            // P*2 + (nf&1)
            int rem = q & 511;
            int lane16 = rem >> 3, j = rem & 7;
            int lg = lane16 >> 4, lr = lane16 & 15;
            int P = sub >> 1, nfh = sub & 1;
            int nf = (region - 2) * 2 + nfh;
            int ell = P * 32 + ((j >> 2) << 4) + lg * 4 + (j & 3);
            v = W2[(nf * 16 + lr) * 2048 + c * 64 + ell];
        }
        ws[WS_FPK + i] = (unsigned short)f2bf(v);
    }
    if (i < 24576) ws[WS_QKV + i] = (unsigned short)f2bf(in_proj_w[i]);
    if (i < 8192)  ws[WS_WO + i]  = (unsigned short)f2bf(out_w[i]);
    if (do_mlp && i < 8192) {
        int row = i >> 6, col = i & 63;
        ws[WS_MW1 + i] = (col < 55) ? (unsigned short)f2bf(mlp_w1[row * 55 + col]) : 0;
        ws[WS_MW2 + i] = (unsigned short)f2bf(mlp_w2[i]);
    }
}

// ---------------------------------------------------------------------------
// Kernel 1 (MFMA): features + feat MLP (unchanged from R3)
// ---------------------------------------------------------------------------
#define FB 16
__global__ __launch_bounds__(320) void k_feat2(
    const int* __restrict__ ai, const int* __restrict__ aj,
    const int* __restrict__ gi, const int* __restrict__ gj,
    const int* __restrict__ walls,
    const unsigned short* __restrict__ w1p,
    const float* __restrict__ b1,
    const unsigned short* __restrict__ w2p,
    const float* __restrict__ b2,
    float* __restrict__ x)
{
    const int tid = threadIdx.x;
    const int ob0 = blockIdx.x * FB;
    __shared__ unsigned char wl[FB * 256];
    __shared__ short fe[80][72];
    __shared__ int t3s[FB][3];

    for (int i = tid; i < FB * 256; i += 320)
        wl[i] = (unsigned char)walls[ob0 * 256 + i];
    __syncthreads();

    const int lane = tid & 63;
    const int wid  = tid >> 6;

    if (wid < 4) {
        #pragma unroll
        for (int q = 0; q < 4; ++q) {
            const int o = wid * 4 + q;
            const unsigned char* wp = wl + o * 256 + lane * 4;
            int m = (wp[0] ? 1 : 0) | (wp[1] ? 2 : 0) | (wp[2] ? 4 : 0) | (wp[3] ? 8 : 0);
            unsigned long long bm[4];
            bm[0] = __ballot(m & 1); bm[1] = __ballot(m & 2);
            bm[2] = __ballot(m & 4); bm[3] = __ballot(m & 8);
            int res[3];
            #pragma unroll
            for (int c = 0; c < 3; ++c) {
                int best = 1 << 30, bj = -1;
                #pragma unroll
                for (int j = 0; j < 4; ++j)
                    if (bm[j]) {
                        int cand = 4 * (int)__builtin_ctzll(bm[j]) + j;
                        if (cand < best) { best = cand; bj = j; }
                    }
                res[c] = (bj >= 0) ? best : 256;
                if (bj >= 0) bm[bj] &= bm[bj] - 1;
            }
            if (lane == 0) {
                t3s[o][0] = res[0]; t3s[o][1] = res[1]; t3s[o][2] = res[2];
            }
        }
    }
    __syncthreads();

    if (tid < 80) {
        const int o = tid / 5, tq = tid % 5;
        const int gob = ob0 + o;
        const unsigned char* wp = wl + o * 256;
        const int mi[5] = {0, -1, 1, 0, 0};
        const int mj[5] = {0, 0, 0, -1, 1};
        const int a_i = ai[gob], a_j = aj[gob];
        int ni = a_i + mi[tq], nj = a_j + mj[tq];
        bool inb = (ni >= 0 && ni < 16 && nj >= 0 && nj < 16);
        int pi = inb ? ni : a_i;
        int pj = inb ? nj : a_j;

        float f[64];
        #pragma unroll
        for (int d = 55; d < 64; ++d) f[d] = 0.f;

        const float ain = 2.f * (float)pi / 15.f - 1.f;
        const float ajn = 2.f * (float)pj / 15.f - 1.f;
        const float gin = 2.f * (float)gi[gob] / 15.f - 1.f;
        const float gjn = 2.f * (float)gj[gob] / 15.f - 1.f;
        const float dxg = gjn - ajn, dyg = gin - ain;
        const float dg = sqrtf(dxg * dxg + dyg * dyg + 1e-8f);
        f[0] = ain; f[1] = ajn; f[2] = gin; f[3] = gjn;
        f[4] = dxg; f[5] = dyg; f[6] = dg; f[7] = dyg / dg; f[8] = dxg / dg;

        #pragma unroll
        for (int w = 0; w < 3; ++w) {
            int idx = t3s[o][w];
            float vm = (idx < 256) ? 1.f : 0.f;
            int safe = (idx < 256) ? idx : 0;
            float win = 2.f * (float)(safe >> 4) / 15.f - 1.f;
            float wjn = 2.f * (float)(safe & 15) / 15.f - 1.f;
            {
                float dx = wjn - ajn, dy = win - ain;
                float d = sqrtf(dx * dx + dy * dy + 1e-8f);
                f[9 + w * 7 + 0] = win * vm; f[9 + w * 7 + 1] = wjn * vm;
                f[9 + w * 7 + 2] = dx * vm;  f[9 + w * 7 + 3] = dy * vm;
                f[9 + w * 7 + 4] = d * vm;
                f[9 + w * 7 + 5] = (dy / d) * vm; f[9 + w * 7 + 6] = (dx / d) * vm;
            }
            {
                float dx = wjn - gjn, dy = win - gin;
                float d = sqrtf(dx * dx + dy * dy + 1e-8f);
                f[30 + w * 7 + 0] = win * vm; f[30 + w * 7 + 1] = wjn * vm;
                f[30 + w * 7 + 2] = dx * vm;  f[30 + w * 7 + 3] = dy * vm;
                f[30 + w * 7 + 4] = d * vm;
                f[30 + w * 7 + 5] = (dy / d) * vm; f[30 + w * 7 + 6] = (dx / d) * vm;
            }
        }
        f[51] = (pi > 0)  ? (float)wp[(pi - 1) * 16 + pj] : 1.f;
        f[52] = (pi < 15) ? (float)wp[(pi + 1) * 16 + pj] : 1.f;
        f[53] = (pj > 0)  ? (float)wp[pi * 16 + (pj - 1)] : 1.f;
        f[54] = (pj < 15) ? (float)wp[pi * 16 + (pj + 1)] : 1.f;

        unsigned* dst = (unsigned*)&fe[tid][0];
        #pragma unroll
        for (int d = 0; d < 32; ++d)
            dst[d] = pk2(f[2 * d], f[2 * d + 1]);
    }
    __syncthreads();

    const int lr = lane & 15;
    const int lg = lane >> 4;
    const int t0 = wid * 16;

    bf16x8 bf0 = *(const bf16x8*)&fe[t0 + lr][lg * 8];
    bf16x8 bf1 = *(const bf16x8*)&fe[t0 + lr][32 + lg * 8];

    f32x4 acc[4] = {};
    #pragma unroll
    for (int hc = 0; hc < 8; ++hc) {
        bf16x8 a0 = *(const bf16x8*)(w1p + (hc * 16 + lr) * 64 + lg * 8);
        bf16x8 a1 = *(const bf16x8*)(w1p + (hc * 16 + lr) * 64 + 32 + lg * 8);
        f32x4 d = {0.f, 0.f, 0.f, 0.f};
        d = MFMA16x32(a0, bf0, d);
        d = MFMA16x32(a1, bf1, d);
        f32x4 b1v = *(const f32x4*)(b1 + hc * 16 + lg * 4);
        bf16x4 h;
        #pragma unroll
        for (int r = 0; r < 4; ++r) {
            float s = d[r] + b1v[r];
            h[r] = f2bf(0.5f * s * (1.f + erff(s * 0.70710678118654752f)));
        }
        #pragma unroll
        for (int nf = 0; nf < 4; ++nf) {
            bf16x4 bw = *(const bf16x4*)(w2p + (nf * 16 + lr) * 128 + hc * 16 + lg * 4);
            acc[nf] = mfma16x16(h, bw, acc[nf]);
        }
    }

    const int gt0 = blockIdx.x * 80 + t0;
    #pragma unroll
    for (int r = 0; r < 4; ++r) {
        const int row = (gt0 + lg * 4 + r) * 64;
        #pragma unroll
        for (int nf = 0; nf < 4; ++nf)
            x[row + nf * 16 + lr] = acc[nf][r] + b2[nf * 16 + lr];
    }
}

// ---------------------------------------------------------------------------
// Fallback kernel 1 (pure VALU)
// ---------------------------------------------------------------------------
__global__ __launch_bounds__(NT) void k_feat(
    const int* __restrict__ ai, const int* __restrict__ aj,
    const int* __restrict__ gi, const int* __restrict__ gj,
    const int* __restrict__ walls,
    const float* __restrict__ w1, const float* __restrict__ b1,
    const float* __restrict__ w2, const float* __restrict__ b2,
    float* __restrict__ xout)
{
    const int b = blockIdx.x;
    const int tid = threadIdx.x;
    __shared__ float wallf[256];
    __shared__ unsigned long long wmask[4];
    __shared__ int   t3[3];
    __shared__ float feats[5][55];
    __shared__ float h1[5][128];

    int wv = walls[b * 256 + tid];
    wallf[tid] = (float)wv;
    unsigned long long bm = __ballot(wv == 1);
    if ((tid & 63) == 0) wmask[tid >> 6] = bm;
    __syncthreads();

    if (tid == 0) {
        int c = 0;
        for (int w = 0; w < 4 && c < 3; ++w) {
            unsigned long long mm = wmask[w];
            while (mm && c < 3) {
                t3[c++] = w * 64 + __builtin_ctzll(mm);
                mm &= mm - 1;
            }
        }
        for (; c < 3; ++c) t3[c] = 256;
    }
    __syncthreads();

    if (tid < 5) {
        const int mi[5] = {0, -1, 1, 0, 0};
        const int mj[5] = {0, 0, 0, -1, 1};
        const int a_i = ai[b], a_j = aj[b];
        int ni = a_i + mi[tid], nj = a_j + mj[tid];
        bool inb = (ni >= 0 && ni < 16 && nj >= 0 && nj < 16);
        int pi = inb ? ni : a_i;
        int pj = inb ? nj : a_j;

        const float ain = 2.f * (float)pi / 15.f - 1.f;
        const float ajn = 2.f * (float)pj / 15.f - 1.f;
        const float gin = 2.f * (float)gi[b] / 15.f - 1.f;
        const float gjn = 2.f * (float)gj[b] / 15.f - 1.f;
        const float dxg = gjn - ajn, dyg = gin - ain;
        const float dg = sqrtf(dxg * dxg + dyg * dyg + 1e-8f);

        float* f = feats[tid];
        f[0] = ain; f[1] = ajn; f[2] = gin; f[3] = gjn;
        f[4] = dxg; f[5] = dyg; f[6] = dg; f[7] = dyg / dg; f[8] = dxg / dg;

        for (int w = 0; w < 3; ++w) {
            int idx = t3[w];
            float vm = (idx < 256) ? 1.f : 0.f;
            int safe = (idx < 256) ? idx : 0;
            float win = 2.f * (float)(safe >> 4) / 15.f - 1.f;
            float wjn = 2.f * (float)(safe & 15) / 15.f - 1.f;
            {
                float dx = wjn - ajn, dy = win - ain;
                float d = sqrtf(dx * dx + dy * dy + 1e-8f);
                float* o = f + 9 + w * 7;
                o[0] = win * vm; o[1] = wjn * vm; o[2] = dx * vm; o[3] = dy * vm;
                o[4] = d * vm;  o[5] = (dy / d) * vm; o[6] = (dx / d) * vm;
            }
            {
                float dx = wjn - gjn, dy = win - gin;
                float d = sqrtf(dx * dx + dy * dy + 1e-8f);
                float* o = f + 30 + w * 7;
                o[0] = win * vm; o[1] = wjn * vm; o[2] = dx * vm; o[3] = dy * vm;
                o[4] = d * vm;  o[5] = (dy / d) * vm; o[6] = (dx / d) * vm;
            }
        }
        f[51] = (pi > 0)  ? wallf[(pi - 1) * 16 + pj] : 1.f;
        f[52] = (pi < 15) ? wallf[(pi + 1) * 16 + pj] : 1.f;
        f[53] = (pj > 0)  ? wallf[pi * 16 + (pj - 1)] : 1.f;
        f[54] = (pj < 15) ? wallf[pi * 16 + (pj + 1)] : 1.f;
    }
    __syncthreads();

    for (int i = tid; i < 640; i += NT) {
        int p = i >> 7, j = i & 127;
        float s = b1[j];
        const float* wr = w1 + j * 55;
        const float* fp = feats[p];
        #pragma unroll
        for (int k = 0; k < 55; ++k) s += fp[k] * wr[k];
        h1[p][j] = 0.5f * s * (1.f + erff(s * 0.70710678118654752f));
    }
    __syncthreads();

    for (int i = tid; i < 320; i += NT) {
        int p = i >> 6, j = i & 63;
        float s = b2[j];
        const float* wr = w2 + j * 128;
        #pragma unroll
        for (int k = 0; k < 128; ++k) s += h1[p][k] * wr[k];
        xout[b * 320 + i] = s;
    }
}

// ---------------------------------------------------------------------------
// Kernel 2 (MFMA, head-per-wave): MHA + residual + LN1 (unchanged from R12)
// ---------------------------------------------------------------------------
__global__ __launch_bounds__(256, 2) void k_att3(
    const float* __restrict__ x, float* __restrict__ xo,
    const unsigned short* __restrict__ wqkv,
    const float* __restrict__ bqkv,
    const unsigned short* __restrict__ wo,
    const float* __restrict__ bo,
    const float* __restrict__ g1, const float* __restrict__ be1)
{
    const int tid  = threadIdx.x;
    const int lane = tid & 63;
    const int wid  = tid >> 6;
    const int lr = lane & 15;
    const int lg = lane >> 4;
    const int o0 = blockIdx.x * 16;

    __shared__ unsigned short o_sh[5][16][68];
    __shared__ float          y_sh[5][16][68];

    bf16x8 bx[5][2];
    #pragma unroll
    for (int tq = 0; tq < 5; ++tq)
        #pragma unroll
        for (int kf = 0; kf < 2; ++kf) {
            const float* p = x + ((o0 + lr) * 5 + tq) * 64 + kf * 32 + lg * 8;
            f32x4 aa = *(const f32x4*)(p);
            f32x4 bb = *(const f32x4*)(p + 4);
            bx[tq][kf] = pk_bf16x8(aa, bb);
        }

    {
        const int h = wid;
        bf16x8 aq[2], ak[2], av[2];
        #pragma unroll
        for (int kf = 0; kf < 2; ++kf) {
            aq[kf] = *(const bf16x8*)(wqkv + (h * 16 + lr) * 64 + kf * 32 + lg * 8);
            ak[kf] = *(const bf16x8*)(wqkv + (64 + h * 16 + lr) * 64 + kf * 32 + lg * 8);
            av[kf] = *(const bf16x8*)(wqkv + (128 + h * 16 + lr) * 64 + kf * 32 + lg * 8);
        }
        f32x4 bq = *(const f32x4*)(bqkv + h * 16 + lg * 4);
        f32x4 bk = *(const f32x4*)(bqkv + 64 + h * 16 + lg * 4);
        f32x4 bv = *(const f32x4*)(bqkv + 128 + h * 16 + lg * 4);

        f32x4 qf[5], kf_[5], vf[5];
        #pragma unroll
        for (int t = 0; t < 5; ++t) {
            f32x4 d = {0.f, 0.f, 0.f, 0.f};
            d = MFMA16x32(aq[0], bx[t][0], d);
            d = MFMA16x32(aq[1], bx[t][1], d);
            qf[t] = d + bq;
            f32x4 e = {0.f, 0.f, 0.f, 0.f};
            e = MFMA16x32(ak[0], bx[t][0], e);
            e = MFMA16x32(ak[1], bx[t][1], e);
            kf_[t] = e + bk;
            f32x4 g = {0.f, 0.f, 0.f, 0.f};
            g = MFMA16x32(av[0], bx[t][0], g);
            g = MFMA16x32(av[1], bx[t][1], g);
            vf[t] = g + bv;
        }

        float p_[5][5];
        #pragma unroll
        for (int tq = 0; tq < 5; ++tq)
            #pragma unroll
            for (int tk = 0; tk < 5; ++tk) {
                float s = qf[tq][0] * kf_[tk][0] + qf[tq][1] * kf_[tk][1]
                        + qf[tq][2] * kf_[tk][2] + qf[tq][3] * kf_[tk][3];
                s += __shfl_xor(s, 16);
                s += __shfl_xor(s, 32);
                p_[tq][tk] = s * 0.25f;
            }
        #pragma unroll
        for (int tq = 0; tq < 5; ++tq) {
            float m = p_[tq][0];
            #pragma unroll
            for (int tk = 1; tk < 5; ++tk) m = fmaxf(m, p_[tq][tk]);
            float sum = 0.f;
            #pragma unroll
            for (int tk = 0; tk < 5; ++tk) {
                float e = __expf(p_[tq][tk] - m);
                p_[tq][tk] = e; sum += e;
            }
            float inv = 1.f / sum;
            #pragma unroll
            for (int tk = 0; tk < 5; ++tk) p_[tq][tk] *= inv;
        }

        #pragma unroll
        for (int tq = 0; tq < 5; ++tq) {
            f32x4 o = {0.f, 0.f, 0.f, 0.f};
            #pragma unroll
            for (int tk = 0; tk < 5; ++tk) o += p_[tq][tk] * vf[tk];
            *(bf16x4*)&o_sh[tq][lr][h * 16 + lg * 4] = pk_bf16(o);
        }
    }
    __syncthreads();

    {
        bf16x4 bwo[4];
        #pragma unroll
        for (int kf = 0; kf < 4; ++kf)
            bwo[kf] = *(const bf16x4*)(wo + (wid * 16 + lr) * 64 + kf * 16 + lg * 4);

        #pragma unroll
        for (int tq = 0; tq < 5; ++tq) {
            f32x4 acc = {0.f, 0.f, 0.f, 0.f};
            #pragma unroll
            for (int kf = 0; kf < 4; ++kf) {
                bf16x4 a2 = *(const bf16x4*)&o_sh[tq][lr][kf * 16 + lg * 4];
                acc = mfma16x16(a2, bwo[kf], acc);
            }
            const int col = wid * 16 + lr;
            const float bv2 = bo[col];
            #pragma unroll
            for (int r = 0; r < 4; ++r) {
                const int obs = lg * 4 + r;
                y_sh[tq][obs][col] =
                    acc[r] + bv2 + x[((o0 + obs) * 5 + tq) * 64 + col];
            }
        }
    }
    __syncthreads();

    {
        const int grp = tid >> 4;
        const int l16 = tid & 15;
        #pragma unroll
        for (int it = 0; it < 5; ++it) {
            const int tq = it, obs = grp;
            f32x4 v = *(const f32x4*)&y_sh[tq][obs][l16 * 4];
            float s = v[0] + v[1] + v[2] + v[3];
            s += __shfl_xor(s, 1); s += __shfl_xor(s, 2);
            s += __shfl_xor(s, 4); s += __shfl_xor(s, 8);
            float mean = s * (1.f / 64.f);
            float q = 0.f;
            #pragma unroll
            for (int j = 0; j < 4; ++j) { float d0 = v[j] - mean; q += d0 * d0; }
            q += __shfl_xor(q, 1); q += __shfl_xor(q, 2);
            q += __shfl_xor(q, 4); q += __shfl_xor(q, 8);
            float rstd = rsqrtf(q * (1.f / 64.f) + 1e-5f);
            const int row = ((o0 + obs) * 5 + tq) * 64;
            #pragma unroll
            for (int j = 0; j < 4; ++j) {
                int c = l16 * 4 + j;
                xo[row + c] = (v[j] - mean) * rstd * g1[c] + be1[c];
            }
        }
    }
}

// ---------------------------------------------------------------------------
// Fallback attention (pure VALU)
// ---------------------------------------------------------------------------
__global__ __launch_bounds__(NT) void k_att(
    float* __restrict__ x,
    const float* __restrict__ wqkv, const float* __restrict__ bqkv,
    const float* __restrict__ wo, const float* __restrict__ bo,
    const float* __restrict__ g1, const float* __restrict__ be1)
{
    const int b = blockIdx.x;
    const int tid = threadIdx.x;
    __shared__ float xs[5][64];
    __shared__ float qkv[5][192];
    __shared__ float att[4][5][5];
    __shared__ float os[5][64];
    __shared__ float xr[5][64];
    __shared__ float stat[5][2];

    for (int i = tid; i < 320; i += NT) xs[i >> 6][i & 63] = x[b * 320 + i];
    __syncthreads();

    for (int i = tid; i < 960; i += NT) {
        int p = i / 192, j = i % 192;
        float s = bqkv[j];
        const float* wr = wqkv + j * 64;
        const float* xm = xs[p];
        #pragma unroll
        for (int k = 0; k < 64; ++k) s += xm[k] * wr[k];
        qkv[p][j] = s;
    }
    __syncthreads();

    if (tid < 100) {
        int h = tid / 25, r = tid % 25, q = r / 5, kk = r % 5;
        float s = 0.f;
        #pragma unroll
        for (int d = 0; d < 16; ++d) s += qkv[q][h * 16 + d] * qkv[kk][64 + h * 16 + d];
        att[h][q][kk] = s * 0.25f;
    }
    __syncthreads();

    if (tid < 20) {
        int h = tid / 5, q = tid % 5;
        float m = att[h][q][0];
        for (int k = 1; k < 5; ++k) m = fmaxf(m, att[h][q][k]);
        float sum = 0.f;
        for (int k = 0; k < 5; ++k) { float e = expf(att[h][q][k] - m); att[h][q][k] = e; sum += e; }
        float inv = 1.f / sum;
        for (int k = 0; k < 5; ++k) att[h][q][k] *= inv;
    }
    __syncthreads();

    for (int i = tid; i < 320; i += NT) {
        int p = i >> 6, c = i & 63, h = c >> 4;
        float s = 0.f;
        #pragma unroll
        for (int k = 0; k < 5; ++k) s += att[h][p][k] * qkv[k][128 + c];
        os[p][c] = s;
    }
    __syncthreads();

    for (int i = tid; i < 320; i += NT) {
        int p = i >> 6, c = i & 63;
        float s = bo[c];
        const float* wr = wo + c * 64;
        const float* om = os[p];
        #pragma unroll
        for (int k = 0; k < 64; ++k) s += om[k] * wr[k];
        xr[p][c] = xs[p][c] + s;
    }
    __syncthreads();

    if (tid < 5) {
        float m = 0.f;
        for (int k = 0; k < 64; ++k) m += xr[tid][k];
        m *= (1.f / 64.f);
        float v = 0.f;
        for (int k = 0; k < 64; ++k) { float d = xr[tid][k] - m; v += d * d; }
        v *= (1.f / 64.f);
        stat[tid][0] = m;
        stat[tid][1] = 1.f / sqrtf(v + 1e-5f);
    }
    __syncthreads();

    for (int i = tid; i < 320; i += NT) {
        int p = i >> 6, c = i & 63;
        x[b * 320 + i] = (xr[p][c] - stat[p][0]) * stat[p][1] * g1[c] + be1[c];
    }
}

// ---------------------------------------------------------------------------
// Kernel 3 (MFMA, wave-split hidden, zero-barrier L2 streaming, v3):
// = R13 k_ffn9 (paired GEMM2 + 16KB reduce) but launch_bounds back to
// (256,2): R13's (256,3) capped VGPR at 84 and destroyed load pipelining
// (k_ffn8's win came from VGPR 120). With LDS=16KB residency is now
// VGPR-bound: ~120 VGPR -> 16 waves/CU = 4 blocks/CU, grid 640 <= 1024
// fully resident. ILP restored + 2x TLP vs k_ffn8.
// ---------------------------------------------------------------------------
#define PKCH 8192
__global__ __launch_bounds__(256, 2) void k_ffn10(
    float* __restrict__ x,
    const unsigned short* __restrict__ wpk,
    const float* __restrict__ b1,
    const float* __restrict__ b2,
    const float* __restrict__ g2, const float* __restrict__ be2)
{
    __shared__ float red[4][4][64][4];     // [wave][nf][lane][r] = 16KB
    const int tid  = threadIdx.x;
    const int lane = tid & 63;
    const int wid  = tid >> 6;
    const int lr = lane & 15;
    const int lg = lane >> 4;
    const int row0 = blockIdx.x * 64;

    bf16x8 bx[4][2];
    #pragma unroll
    for (int mf = 0; mf < 4; ++mf)
        #pragma unroll
        for (int kk = 0; kk < 2; ++kk) {
            const float* p = x + (row0 + mf * 16 + lr) * 64 + kk * 32 + lg * 8;
            f32x4 aa = *(const f32x4*)(p);
            f32x4 bb = *(const f32x4*)(p + 4);
            bx[mf][kk] = pk_bf16x8(aa, bb);
        }

    f32x4 acc[4][4] = {};
    const int fbase = (lg * 16 + lr) * 8;
    const unsigned short* wp = wpk + (wid * 8) * PKCH;
    const float* b1w = b1 + wid * 512;

    for (int c = 0; c < 8; ++c) {
        const unsigned short* L = wp + c * PKCH;
        bf16x8 rA[4], rB[4], rW[2][4];
        #pragma unroll
        for (int hc = 0; hc < 4; ++hc) {
            rA[hc] = *(const bf16x8*)&L[hc * 512 + fbase];
            rB[hc] = *(const bf16x8*)&L[2048 + hc * 512 + fbase];
        }
        #pragma unroll
        for (int P = 0; P < 2; ++P)
            #pragma unroll
            for (int nf = 0; nf < 4; ++nf)
                rW[P][nf] = *(const bf16x8*)
                    &L[4096 + (nf >> 1) * 2048 + (P * 2 + (nf & 1)) * 512 + fbase];
        f32x4 b1v[4];
        #pragma unroll
        for (int hc = 0; hc < 4; ++hc)
            b1v[hc] = *(const f32x4*)(b1w + c * 64 + hc * 16 + lg * 4);

        #pragma unroll
        for (int mf = 0; mf < 4; ++mf) {
            bf16x4 h[4];
            #pragma unroll
            for (int hc = 0; hc < 4; ++hc) {
                f32x4 d = MFMA16x32(rA[hc], bx[mf][0], b1v[hc]);
                d = MFMA16x32(rB[hc], bx[mf][1], d);
                #pragma unroll
                for (int r = 0; r < 4; ++r) d[r] = fmaxf(d[r], 0.f);
                h[hc] = pk_bf16(d);
            }
            #pragma unroll
            for (int P = 0; P < 2; ++P) {
                bf16x8 hp = cat44(h[2 * P], h[2 * P + 1]);
                acc[mf][0] = MFMA16x32(hp, rW[P][0], acc[mf][0]);
                acc[mf][1] = MFMA16x32(hp, rW[P][1], acc[mf][1]);
                acc[mf][2] = MFMA16x32(hp, rW[P][2], acc[mf][2]);
                acc[mf][3] = MFMA16x32(hp, rW[P][3], acc[mf][3]);
            }
        }
    }

    // 4-pass cross-wave reduction + epilogue (wave m owns rows mf=m)
    for (int m = 0; m < 4; ++m) {
        #pragma unroll
        for (int nf = 0; nf < 4; ++nf)
            *(f32x4*)&red[wid][nf][lane][0] = acc[m][nf];
        __syncthreads();
        if (wid == m) {
            f32x4 vr[4];
            #pragma unroll
            for (int nf = 0; nf < 4; ++nf) {
                f32x4 s0 = *(const f32x4*)&red[0][nf][lane][0];
                f32x4 s1 = *(const f32x4*)&red[1][nf][lane][0];
                f32x4 s2 = *(const f32x4*)&red[2][nf][lane][0];
                f32x4 s3 = *(const f32x4*)&red[3][nf][lane][0];
                vr[nf] = (s0 + s1) + (s2 + s3);
            }
            #pragma unroll
            for (int r = 0; r < 4; ++r) {
                const int mm = row0 + m * 16 + lg * 4 + r;
                float v[4];
                float s = 0.f;
                #pragma unroll
                for (int nf = 0; nf < 4; ++nf) {
                    int cc = nf * 16 + lr;
                    float y = vr[nf][r] + b2[cc] + x[mm * 64 + cc];
                    v[nf] = y; s += y;
                }
                s += __shfl_xor(s, 1); s += __shfl_xor(s, 2);
                s += __shfl_xor(s, 4); s += __shfl_xor(s, 8);
                float mean = s * (1.f / 64.f);
                float q = 0.f;
                #pragma unroll
                for (int nf = 0; nf < 4; ++nf) { float d0 = v[nf] - mean; q += d0 * d0; }
                q += __shfl_xor(q, 1); q += __shfl_xor(q, 2);
                q += __shfl_xor(q, 4); q += __shfl_xor(q, 8);
                float rstd = rsqrtf(q * (1.f / 64.f) + 1e-5f);
                #pragma unroll
                for (int nf = 0; nf < 4; ++nf) {
                    int cc = nf * 16 + lr;
                    x[mm * 64 + cc] = (v[nf] - mean) * rstd * g2[cc] + be2[cc];
                }
            }
        }
        __syncthreads();
    }
}

// ---------------------------------------------------------------------------
// Fallback FFN (pure VALU)
// ---------------------------------------------------------------------------
#define GRP 8
#define ROWS (GRP * 5)
__global__ __launch_bounds__(NT) void k_ffn(
    float* __restrict__ x,
    const float* __restrict__ w1, const float* __restrict__ b1,
    const float* __restrict__ w2, const float* __restrict__ b2,
    const float* __restrict__ g2, const float* __restrict__ be2)
{
    const int tid = threadIdx.x;
    const int base = blockIdx.x * (ROWS * 64);
    __shared__ float xs[ROWS][64];
    __shared__ float hch[ROWS][128];
    __shared__ float stat[ROWS][2];

    for (int i = tid; i < ROWS * 64; i += NT) xs[i >> 6][i & 63] = x[base + i];
    __syncthreads();

    const int c = tid & 63;
    const int g = tid >> 6;
    float acc[10];
    #pragma unroll
    for (int r = 0; r < 10; ++r) acc[r] = 0.f;

    for (int ch = 0; ch < 16; ++ch) {
        for (int ii = tid; ii < ROWS * 128; ii += NT) {
            int m = ii >> 7, j = ii & 127;
            int jj = (ch << 7) + j;
            float s = b1[jj];
            const float* wr = w1 + jj * 64;
            const float* xm = xs[m];
            #pragma unroll
            for (int k = 0; k < 64; ++k) s += xm[k] * wr[k];
            hch[m][j] = fmaxf(s, 0.f);
        }
        __syncthreads();
        const float* w2r = w2 + c * 2048 + (ch << 7);
        for (int j = 0; j < 128; ++j) {
            float wv = w2r[j];
            #pragma unroll
            for (int r = 0; r < 10; ++r) acc[r] += hch[g * 10 + r][j] * wv;
        }
        __syncthreads();
    }

    #pragma unroll
    for (int r = 0; r < 10; ++r) {
        int m = g * 10 + r;
        hch[m][c] = acc[r] + b2[c] + xs[m][c];
    }
    __syncthreads();

    if (tid < ROWS) {
        float m = 0.f;
        for (int k = 0; k < 64; ++k) m += hch[tid][k];
        m *= (1.f / 64.f);
        float v = 0.f;
        for (int k = 0; k < 64; ++k) { float d = hch[tid][k] - m; v += d * d; }
        v *= (1.f / 64.f);
        stat[tid][0] = m;
        stat[tid][1] = 1.f / sqrtf(v + 1e-5f);
    }
    __syncthreads();

    for (int i = tid; i < ROWS * 64; i += NT) {
        int m = i >> 6, cc = i & 63;
        x[base + i] = (hch[m][cc] - stat[m][0]) * stat[m][1] * g2[cc] + be2[cc];
    }
}

// ---------------------------------------------------------------------------
extern "C" void kernel_launch(void* const* d_in, const int* in_sizes, int n_in,
                              void* d_out, int out_size, void* d_ws, size_t ws_size,
                              hipStream_t stream)
{
    (void)in_sizes; (void)n_in; (void)out_size;
    const int*   ai       = (const int*)d_in[0];
    const int*   aj       = (const int*)d_in[1];
    const int*   gi       = (const int*)d_in[2];
    const int*   gj       = (const int*)d_in[3];
    const int*   walls    = (const int*)d_in[4];
    const float* mlp_w1   = (const float*)d_in[5];
    const float* mlp_b1   = (const float*)d_in[6];
    const float* mlp_w2   = (const float*)d_in[7];
    const float* mlp_b2   = (const float*)d_in[8];
    const float* in_proj_w = (const float*)d_in[9];
    const float* in_proj_b = (const float*)d_in[10];
    const float* out_w    = (const float*)d_in[11];
    const float* out_b    = (const float*)d_in[12];
    const float* ln1_g    = (const float*)d_in[13];
    const float* ln1_b    = (const float*)d_in[14];
    const float* ln2_g    = (const float*)d_in[15];
    const float* ln2_b    = (const float*)d_in[16];
    const float* ffn_w1   = (const float*)d_in[17];
    const float* ffn_b1   = (const float*)d_in[18];
    const float* ffn_w2   = (const float*)d_in[19];
    const float* ffn_b2   = (const float*)d_in[20];

    float* x = (float*)d_out;
    const int B = 8192;
    const bool fast  = ws_size >= (size_t)(WS_BASE * 2);
    const bool fast2 = ws_size >= (size_t)(WS_TOTAL * 2);
    unsigned short* wsbf = (unsigned short*)d_ws;

    if (fast)
        k_cvtw<<<2048, NT, 0, stream>>>(ffn_w1, ffn_w2, in_proj_w, out_w,
                                        mlp_w1, mlp_w2, fast2 ? 1 : 0, wsbf);

    if (fast2) {
        k_feat2<<<B / FB, 320, 0, stream>>>(ai, aj, gi, gj, walls,
            wsbf + WS_MW1, mlp_b1, wsbf + WS_MW2, mlp_b2, x);
    } else {
        k_feat<<<B, NT, 0, stream>>>(ai, aj, gi, gj, walls,
                                     mlp_w1, mlp_b1, mlp_w2, mlp_b2, x);
    }

    for (int l = 0; l < 2; ++l) {
        if (fast) {
            k_att3<<<512, 256, 0, stream>>>(x, x,
                wsbf + WS_QKV + l * 12288, in_proj_b + l * 192,
                wsbf + WS_WO + l * 4096, out_b + l * 64,
                ln1_g + l * 64, ln1_b + l * 64);
            k_ffn10<<<640, 256, 0, stream>>>(x,
                wsbf + WS_FPK + l * 262144, ffn_b1 + l * 2048,
                ffn_b2 + l * 64,
                ln2_g + l * 64, ln2_b + l * 64);
        } else {
            k_att<<<B, NT, 0, stream>>>(x,
                in_proj_w + l * 192 * 64, in_proj_b + l * 192,
                out_w + l * 64 * 64, out_b + l * 64,
                ln1_g + l * 64, ln1_b + l * 64);
            k_ffn<<<B / GRP, NT, 0, stream>>>(x,
                ffn_w1 + l * 2048 * 64, ffn_b1 + l * 2048,
                ffn_w2 + l * 64 * 2048, ffn_b2 + l * 64,
                ln2_g + l * 64, ln2_b + l * 64);
        }
    }
}

// Round 16
// 149.141 us; speedup vs baseline: 1.2111x; 1.2111x over previous
//
#include <hip/hip_runtime.h>
#include <math.h>

#define NT 256

typedef __attribute__((ext_vector_type(4))) float  f32x4;
typedef __attribute__((ext_vector_type(8))) short  bf16x8;
typedef __attribute__((ext_vector_type(4))) short  bf16x4;

static __device__ __forceinline__ short f2bf(float f) {
    unsigned u = __builtin_bit_cast(unsigned, f);
    unsigned r = (u + 0x7fffu + ((u >> 16) & 1u)) >> 16;
    return (short)r;
}

// round-to-nearest-even bf16 pair-pack, pure VALU (no asm, no union)
static __device__ __forceinline__ unsigned pk2(float a, float b) {
    unsigned ua = __builtin_bit_cast(unsigned, a);
    unsigned ub = __builtin_bit_cast(unsigned, b);
    ua = (ua + 0x7fffu + ((ua >> 16) & 1u)) >> 16;
    ub = (ub + 0x7fffu + ((ub >> 16) & 1u)) & 0xffff0000u;
    return ua | ub;
}
static __device__ __forceinline__ bf16x4 pk_bf16(f32x4 d) {
    uint2 t;
    t.x = pk2(d[0], d[1]);
    t.y = pk2(d[2], d[3]);
    return __builtin_bit_cast(bf16x4, t);
}
static __device__ __forceinline__ bf16x8 pk_bf16x8(f32x4 a, f32x4 b) {
    uint4 t;
    t.x = pk2(a[0], a[1]);
    t.y = pk2(a[2], a[3]);
    t.z = pk2(b[0], b[1]);
    t.w = pk2(b[2], b[3]);
    return __builtin_bit_cast(bf16x8, t);
}
static __device__ __forceinline__ bf16x4 lo4(bf16x8 v) {
    return __builtin_shufflevector(v, v, 0, 1, 2, 3);
}
static __device__ __forceinline__ bf16x4 hi4(bf16x8 v) {
    return __builtin_shufflevector(v, v, 4, 5, 6, 7);
}

#define MFMA16x32(a, b, c) __builtin_amdgcn_mfma_f32_16x16x32_bf16(a, b, c, 0, 0, 0)

#if __has_builtin(__builtin_amdgcn_mfma_f32_16x16x16bf16_1k)
static __device__ __forceinline__ f32x4 mfma16x16(bf16x4 a, bf16x4 b, f32x4 c) {
    return __builtin_amdgcn_mfma_f32_16x16x16bf16_1k(a, b, c, 0, 0, 0);
}
#elif __has_builtin(__builtin_amdgcn_mfma_f32_16x16x16_bf16)
static __device__ __forceinline__ f32x4 mfma16x16(bf16x4 a, bf16x4 b, f32x4 c) {
    return __builtin_amdgcn_mfma_f32_16x16x16_bf16(a, b, c, 0, 0, 0);
}
#else
static __device__ __forceinline__ f32x4 mfma16x16(bf16x4 a, bf16x4 b, f32x4 c) {
    f32x4 d;
    asm("v_mfma_f32_16x16x16_bf16 %0, %1, %2, %3" : "=v"(d) : "v"(a), "v"(b), "v"(c));
    return d;
}
#endif

// ws layout (units: unsigned short):
// WS_FPK: packed FFN weights, chunk-major fragment order, [2 layers][32 chunks][8192]
//   per chunk: region A(2048)=W1 cols 0..31 frag-order, B(2048)=W1 cols 32..63,
//              C(2048)=W2 nf0/1, D(2048)=W2 nf2/3.  lane = hc*64+lg*16+lr, j=0..7.
#define WS_FPK  0           // (524288)
#define WS_QKV  524288      // in_proj_w [2][192][64]  (24576)
#define WS_WO   548864      // out_w [2][64][64]       (8192)
#define WS_BASE 557056
#define WS_MW1  557056      // mlp_w1 padded [128][64] (8192)
#define WS_MW2  565248      // mlp_w2 [64][128]        (8192)
#define WS_TOTAL 573440

// ---------------------------------------------------------------------------
// Kernel 0: convert + pack weights to bf16 in d_ws (R11/R12 unpaired layout)
// ---------------------------------------------------------------------------
__global__ __launch_bounds__(NT) void k_cvtw(
    const float* __restrict__ ffn_w1, const float* __restrict__ ffn_w2,
    const float* __restrict__ in_proj_w, const float* __restrict__ out_w,
    const float* __restrict__ mlp_w1, const float* __restrict__ mlp_w2,
    int do_mlp,
    unsigned short* __restrict__ ws)
{
    int i = blockIdx.x * NT + threadIdx.x;
    if (i < 524288) {
        int l = i >> 18;
        int w = i & 262143;
        int c = w >> 13;
        int ww = w & 8191;
        int region = ww >> 11;
        int q = ww & 2047;
        int lane = q >> 3, j = q & 7;
        int hc = lane >> 6, lg = (lane >> 4) & 3, lr = lane & 15;
        const float* W1 = ffn_w1 + l * 131072;   // [2048][64]
        const float* W2 = ffn_w2 + l * 131072;   // [64][2048]
        float v;
        if (region == 0)
            v = W1[(c * 64 + hc * 16 + lr) * 64 + lg * 8 + j];
        else if (region == 1)
            v = W1[(c * 64 + hc * 16 + lr) * 64 + 32 + lg * 8 + j];
        else {
            int nf = ((region - 2) << 1) + (j >> 2);
            int r = j & 3;
            v = W2[(nf * 16 + lr) * 2048 + c * 64 + hc * 16 + lg * 4 + r];
        }
        ws[WS_FPK + i] = (unsigned short)f2bf(v);
    }
    if (i < 24576) ws[WS_QKV + i] = (unsigned short)f2bf(in_proj_w[i]);
    if (i < 8192)  ws[WS_WO + i]  = (unsigned short)f2bf(out_w[i]);
    if (do_mlp && i < 8192) {
        int row = i >> 6, col = i & 63;
        ws[WS_MW1 + i] = (col < 55) ? (unsigned short)f2bf(mlp_w1[row * 55 + col]) : 0;
        ws[WS_MW2 + i] = (unsigned short)f2bf(mlp_w2[i]);
    }
}

// ---------------------------------------------------------------------------
// Kernel 1 (MFMA): features + feat MLP (unchanged from R3)
// ---------------------------------------------------------------------------
#define FB 16
__global__ __launch_bounds__(320) void k_feat2(
    const int* __restrict__ ai, const int* __restrict__ aj,
    const int* __restrict__ gi, const int* __restrict__ gj,
    const int* __restrict__ walls,
    const unsigned short* __restrict__ w1p,
    const float* __restrict__ b1,
    const unsigned short* __restrict__ w2p,
    const float* __restrict__ b2,
    float* __restrict__ x)
{
    const int tid = threadIdx.x;
    const int ob0 = blockIdx.x * FB;
    __shared__ unsigned char wl[FB * 256];
    __shared__ short fe[80][72];
    __shared__ int t3s[FB][3];

    for (int i = tid; i < FB * 256; i += 320)
        wl[i] = (unsigned char)walls[ob0 * 256 + i];
    __syncthreads();

    const int lane = tid & 63;
    const int wid  = tid >> 6;

    if (wid < 4) {
        #pragma unroll
        for (int q = 0; q < 4; ++q) {
            const int o = wid * 4 + q;
            const unsigned char* wp = wl + o * 256 + lane * 4;
            int m = (wp[0] ? 1 : 0) | (wp[1] ? 2 : 0) | (wp[2] ? 4 : 0) | (wp[3] ? 8 : 0);
            unsigned long long bm[4];
            bm[0] = __ballot(m & 1); bm[1] = __ballot(m & 2);
            bm[2] = __ballot(m & 4); bm[3] = __ballot(m & 8);
            int res[3];
            #pragma unroll
            for (int c = 0; c < 3; ++c) {
                int best = 1 << 30, bj = -1;
                #pragma unroll
                for (int j = 0; j < 4; ++j)
                    if (bm[j]) {
                        int cand = 4 * (int)__builtin_ctzll(bm[j]) + j;
                        if (cand < best) { best = cand; bj = j; }
                    }
                res[c] = (bj >= 0) ? best : 256;
                if (bj >= 0) bm[bj] &= bm[bj] - 1;
            }
            if (lane == 0) {
                t3s[o][0] = res[0]; t3s[o][1] = res[1]; t3s[o][2] = res[2];
            }
        }
    }
    __syncthreads();

    if (tid < 80) {
        const int o = tid / 5, tq = tid % 5;
        const int gob = ob0 + o;
        const unsigned char* wp = wl + o * 256;
        const int mi[5] = {0, -1, 1, 0, 0};
        const int mj[5] = {0, 0, 0, -1, 1};
        const int a_i = ai[gob], a_j = aj[gob];
        int ni = a_i + mi[tq], nj = a_j + mj[tq];
        bool inb = (ni >= 0 && ni < 16 && nj >= 0 && nj < 16);
        int pi = inb ? ni : a_i;
        int pj = inb ? nj : a_j;

        float f[64];
        #pragma unroll
        for (int d = 55; d < 64; ++d) f[d] = 0.f;

        const float ain = 2.f * (float)pi / 15.f - 1.f;
        const float ajn = 2.f * (float)pj / 15.f - 1.f;
        const float gin = 2.f * (float)gi[gob] / 15.f - 1.f;
        const float gjn = 2.f * (float)gj[gob] / 15.f - 1.f;
        const float dxg = gjn - ajn, dyg = gin - ain;
        const float dg = sqrtf(dxg * dxg + dyg * dyg + 1e-8f);
        f[0] = ain; f[1] = ajn; f[2] = gin; f[3] = gjn;
        f[4] = dxg; f[5] = dyg; f[6] = dg; f[7] = dyg / dg; f[8] = dxg / dg;

        #pragma unroll
        for (int w = 0; w < 3; ++w) {
            int idx = t3s[o][w];
            float vm = (idx < 256) ? 1.f : 0.f;
            int safe = (idx < 256) ? idx : 0;
            float win = 2.f * (float)(safe >> 4) / 15.f - 1.f;
            float wjn = 2.f * (float)(safe & 15) / 15.f - 1.f;
            {
                float dx = wjn - ajn, dy = win - ain;
                float d = sqrtf(dx * dx + dy * dy + 1e-8f);
                f[9 + w * 7 + 0] = win * vm; f[9 + w * 7 + 1] = wjn * vm;
                f[9 + w * 7 + 2] = dx * vm;  f[9 + w * 7 + 3] = dy * vm;
                f[9 + w * 7 + 4] = d * vm;
                f[9 + w * 7 + 5] = (dy / d) * vm; f[9 + w * 7 + 6] = (dx / d) * vm;
            }
            {
                float dx = wjn - gjn, dy = win - gin;
                float d = sqrtf(dx * dx + dy * dy + 1e-8f);
                f[30 + w * 7 + 0] = win * vm; f[30 + w * 7 + 1] = wjn * vm;
                f[30 + w * 7 + 2] = dx * vm;  f[30 + w * 7 + 3] = dy * vm;
                f[30 + w * 7 + 4] = d * vm;
                f[30 + w * 7 + 5] = (dy / d) * vm; f[30 + w * 7 + 6] = (dx / d) * vm;
            }
        }
        f[51] = (pi > 0)  ? (float)wp[(pi - 1) * 16 + pj] : 1.f;
        f[52] = (pi < 15) ? (float)wp[(pi + 1) * 16 + pj] : 1.f;
        f[53] = (pj > 0)  ? (float)wp[pi * 16 + (pj - 1)] : 1.f;
        f[54] = (pj < 15) ? (float)wp[pi * 16 + (pj + 1)] : 1.f;

        unsigned* dst = (unsigned*)&fe[tid][0];
        #pragma unroll
        for (int d = 0; d < 32; ++d)
            dst[d] = pk2(f[2 * d], f[2 * d + 1]);
    }
    __syncthreads();

    const int lr = lane & 15;
    const int lg = lane >> 4;
    const int t0 = wid * 16;

    bf16x8 bf0 = *(const bf16x8*)&fe[t0 + lr][lg * 8];
    bf16x8 bf1 = *(const bf16x8*)&fe[t0 + lr][32 + lg * 8];

    f32x4 acc[4] = {};
    #pragma unroll
    for (int hc = 0; hc < 8; ++hc) {
        bf16x8 a0 = *(const bf16x8*)(w1p + (hc * 16 + lr) * 64 + lg * 8);
        bf16x8 a1 = *(const bf16x8*)(w1p + (hc * 16 + lr) * 64 + 32 + lg * 8);
        f32x4 d = {0.f, 0.f, 0.f, 0.f};
        d = MFMA16x32(a0, bf0, d);
        d = MFMA16x32(a1, bf1, d);
        f32x4 b1v = *(const f32x4*)(b1 + hc * 16 + lg * 4);
        bf16x4 h;
        #pragma unroll
        for (int r = 0; r < 4; ++r) {
            float s = d[r] + b1v[r];
            h[r] = f2bf(0.5f * s * (1.f + erff(s * 0.70710678118654752f)));
        }
        #pragma unroll
        for (int nf = 0; nf < 4; ++nf) {
            bf16x4 bw = *(const bf16x4*)(w2p + (nf * 16 + lr) * 128 + hc * 16 + lg * 4);
            acc[nf] = mfma16x16(h, bw, acc[nf]);
        }
    }

    const int gt0 = blockIdx.x * 80 + t0;
    #pragma unroll
    for (int r = 0; r < 4; ++r) {
        const int row = (gt0 + lg * 4 + r) * 64;
        #pragma unroll
        for (int nf = 0; nf < 4; ++nf)
            x[row + nf * 16 + lr] = acc[nf][r] + b2[nf * 16 + lr];
    }
}

// ---------------------------------------------------------------------------
// Fallback kernel 1 (pure VALU)
// ---------------------------------------------------------------------------
__global__ __launch_bounds__(NT) void k_feat(
    const int* __restrict__ ai, const int* __restrict__ aj,
    const int* __restrict__ gi, const int* __restrict__ gj,
    const int* __restrict__ walls,
    const float* __restrict__ w1, const float* __restrict__ b1,
    const float* __restrict__ w2, const float* __restrict__ b2,
    float* __restrict__ xout)
{
    const int b = blockIdx.x;
    const int tid = threadIdx.x;
    __shared__ float wallf[256];
    __shared__ unsigned long long wmask[4];
    __shared__ int   t3[3];
    __shared__ float feats[5][55];
    __shared__ float h1[5][128];

    int wv = walls[b * 256 + tid];
    wallf[tid] = (float)wv;
    unsigned long long bm = __ballot(wv == 1);
    if ((tid & 63) == 0) wmask[tid >> 6] = bm;
    __syncthreads();

    if (tid == 0) {
        int c = 0;
        for (int w = 0; w < 4 && c < 3; ++w) {
            unsigned long long mm = wmask[w];
            while (mm && c < 3) {
                t3[c++] = w * 64 + __builtin_ctzll(mm);
                mm &= mm - 1;
            }
        }
        for (; c < 3; ++c) t3[c] = 256;
    }
    __syncthreads();

    if (tid < 5) {
        const int mi[5] = {0, -1, 1, 0, 0};
        const int mj[5] = {0, 0, 0, -1, 1};
        const int a_i = ai[b], a_j = aj[b];
        int ni = a_i + mi[tid], nj = a_j + mj[tid];
        bool inb = (ni >= 0 && ni < 16 && nj >= 0 && nj < 16);
        int pi = inb ? ni : a_i;
        int pj = inb ? nj : a_j;

        const float ain = 2.f * (float)pi / 15.f - 1.f;
        const float ajn = 2.f * (float)pj / 15.f - 1.f;
        const float gin = 2.f * (float)gi[b] / 15.f - 1.f;
        const float gjn = 2.f * (float)gj[b] / 15.f - 1.f;
        const float dxg = gjn - ajn, dyg = gin - ain;
        const float dg = sqrtf(dxg * dxg + dyg * dyg + 1e-8f);

        float* f = feats[tid];
        f[0] = ain; f[1] = ajn; f[2] = gin; f[3] = gjn;
        f[4] = dxg; f[5] = dyg; f[6] = dg; f[7] = dyg / dg; f[8] = dxg / dg;

        for (int w = 0; w < 3; ++w) {
            int idx = t3[w];
            float vm = (idx < 256) ? 1.f : 0.f;
            int safe = (idx < 256) ? idx : 0;
            float win = 2.f * (float)(safe >> 4) / 15.f - 1.f;
            float wjn = 2.f * (float)(safe & 15) / 15.f - 1.f;
            {
                float dx = wjn - ajn, dy = win - ain;
                float d = sqrtf(dx * dx + dy * dy + 1e-8f);
                float* o = f + 9 + w * 7;
                o[0] = win * vm; o[1] = wjn * vm; o[2] = dx * vm; o[3] = dy * vm;
                o[4] = d * vm;  o[5] = (dy / d) * vm; o[6] = (dx / d) * vm;
            }
            {
                float dx = wjn - gjn, dy = win - gin;
                float d = sqrtf(dx * dx + dy * dy + 1e-8f);
                float* o = f + 30 + w * 7;
                o[0] = win * vm; o[1] = wjn * vm; o[2] = dx * vm; o[3] = dy * vm;
                o[4] = d * vm;  o[5] = (dy / d) * vm; o[6] = (dx / d) * vm;
            }
        }
        f[51] = (pi > 0)  ? wallf[(pi - 1) * 16 + pj] : 1.f;
        f[52] = (pi < 15) ? wallf[(pi + 1) * 16 + pj] : 1.f;
        f[53] = (pj > 0)  ? wallf[pi * 16 + (pj - 1)] : 1.f;
        f[54] = (pj < 15) ? wallf[pi * 16 + (pj + 1)] : 1.f;
    }
    __syncthreads();

    for (int i = tid; i < 640; i += NT) {
        int p = i >> 7, j = i & 127;
        float s = b1[j];
        const float* wr = w1 + j * 55;
        const float* fp = feats[p];
        #pragma unroll
        for (int k = 0; k < 55; ++k) s += fp[k] * wr[k];
        h1[p][j] = 0.5f * s * (1.f + erff(s * 0.70710678118654752f));
    }
    __syncthreads();

    for (int i = tid; i < 320; i += NT) {
        int p = i >> 6, j = i & 63;
        float s = b2[j];
        const float* wr = w2 + j * 128;
        #pragma unroll
        for (int k = 0; k < 128; ++k) s += h1[p][k] * wr[k];
        xout[b * 320 + i] = s;
    }
}

// ---------------------------------------------------------------------------
// Kernel 2 (MFMA, head-per-wave): MHA + residual + LN1 (R12, proven)
// ---------------------------------------------------------------------------
__global__ __launch_bounds__(256, 2) void k_att3(
    const float* __restrict__ x, float* __restrict__ xo,
    const unsigned short* __restrict__ wqkv,
    const float* __restrict__ bqkv,
    const unsigned short* __restrict__ wo,
    const float* __restrict__ bo,
    const float* __restrict__ g1, const float* __restrict__ be1)
{
    const int tid  = threadIdx.x;
    const int lane = tid & 63;
    const int wid  = tid >> 6;
    const int lr = lane & 15;
    const int lg = lane >> 4;
    const int o0 = blockIdx.x * 16;

    __shared__ unsigned short o_sh[5][16][68];
    __shared__ float          y_sh[5][16][68];

    bf16x8 bx[5][2];
    #pragma unroll
    for (int tq = 0; tq < 5; ++tq)
        #pragma unroll
        for (int kf = 0; kf < 2; ++kf) {
            const float* p = x + ((o0 + lr) * 5 + tq) * 64 + kf * 32 + lg * 8;
            f32x4 aa = *(const f32x4*)(p);
            f32x4 bb = *(const f32x4*)(p + 4);
            bx[tq][kf] = pk_bf16x8(aa, bb);
        }

    {
        const int h = wid;
        bf16x8 aq[2], ak[2], av[2];
        #pragma unroll
        for (int kf = 0; kf < 2; ++kf) {
            aq[kf] = *(const bf16x8*)(wqkv + (h * 16 + lr) * 64 + kf * 32 + lg * 8);
            ak[kf] = *(const bf16x8*)(wqkv + (64 + h * 16 + lr) * 64 + kf * 32 + lg * 8);
            av[kf] = *(const bf16x8*)(wqkv + (128 + h * 16 + lr) * 64 + kf * 32 + lg * 8);
        }
        f32x4 bq = *(const f32x4*)(bqkv + h * 16 + lg * 4);
        f32x4 bk = *(const f32x4*)(bqkv + 64 + h * 16 + lg * 4);
        f32x4 bv = *(const f32x4*)(bqkv + 128 + h * 16 + lg * 4);

        f32x4 qf[5], kf_[5], vf[5];
        #pragma unroll
        for (int t = 0; t < 5; ++t) {
            f32x4 d = {0.f, 0.f, 0.f, 0.f};
            d = MFMA16x32(aq[0], bx[t][0], d);
            d = MFMA16x32(aq[1], bx[t][1], d);
            qf[t] = d + bq;
            f32x4 e = {0.f, 0.f, 0.f, 0.f};
            e = MFMA16x32(ak[0], bx[t][0], e);
            e = MFMA16x32(ak[1], bx[t][1], e);
            kf_[t] = e + bk;
            f32x4 g = {0.f, 0.f, 0.f, 0.f};
            g = MFMA16x32(av[0], bx[t][0], g);
            g = MFMA16x32(av[1], bx[t][1], g);
            vf[t] = g + bv;
        }

        float p_[5][5];
        #pragma unroll
        for (int tq = 0; tq < 5; ++tq)
            #pragma unroll
            for (int tk = 0; tk < 5; ++tk) {
                float s = qf[tq][0] * kf_[tk][0] + qf[tq][1] * kf_[tk][1]
                        + qf[tq][2] * kf_[tk][2] + qf[tq][3] * kf_[tk][3];
                s += __shfl_xor(s, 16);
                s += __shfl_xor(s, 32);
                p_[tq][tk] = s * 0.25f;
            }
        #pragma unroll
        for (int tq = 0; tq < 5; ++tq) {
            float m = p_[tq][0];
            #pragma unroll
            for (int tk = 1; tk < 5; ++tk) m = fmaxf(m, p_[tq][tk]);
            float sum = 0.f;
            #pragma unroll
            for (int tk = 0; tk < 5; ++tk) {
                float e = __expf(p_[tq][tk] - m);
                p_[tq][tk] = e; sum += e;
            }
            float inv = 1.f / sum;
            #pragma unroll
            for (int tk = 0; tk < 5; ++tk) p_[tq][tk] *= inv;
        }

        #pragma unroll
        for (int tq = 0; tq < 5; ++tq) {
            f32x4 o = {0.f, 0.f, 0.f, 0.f};
            #pragma unroll
            for (int tk = 0; tk < 5; ++tk) o += p_[tq][tk] * vf[tk];
            *(bf16x4*)&o_sh[tq][lr][h * 16 + lg * 4] = pk_bf16(o);
        }
    }
    __syncthreads();

    {
        bf16x4 bwo[4];
        #pragma unroll
        for (int kf = 0; kf < 4; ++kf)
            bwo[kf] = *(const bf16x4*)(wo + (wid * 16 + lr) * 64 + kf * 16 + lg * 4);

        #pragma unroll
        for (int tq = 0; tq < 5; ++tq) {
            f32x4 acc = {0.f, 0.f, 0.f, 0.f};
            #pragma unroll
            for (int kf = 0; kf < 4; ++kf) {
                bf16x4 a2 = *(const bf16x4*)&o_sh[tq][lr][kf * 16 + lg * 4];
                acc = mfma16x16(a2, bwo[kf], acc);
            }
            const int col = wid * 16 + lr;
            const float bv2 = bo[col];
            #pragma unroll
            for (int r = 0; r < 4; ++r) {
                const int obs = lg * 4 + r;
                y_sh[tq][obs][col] =
                    acc[r] + bv2 + x[((o0 + obs) * 5 + tq) * 64 + col];
            }
        }
    }
    __syncthreads();

    {
        const int grp = tid >> 4;
        const int l16 = tid & 15;
        #pragma unroll
        for (int it = 0; it < 5; ++it) {
            const int tq = it, obs = grp;
            f32x4 v = *(const f32x4*)&y_sh[tq][obs][l16 * 4];
            float s = v[0] + v[1] + v[2] + v[3];
            s += __shfl_xor(s, 1); s += __shfl_xor(s, 2);
            s += __shfl_xor(s, 4); s += __shfl_xor(s, 8);
            float mean = s * (1.f / 64.f);
            float q = 0.f;
            #pragma unroll
            for (int j = 0; j < 4; ++j) { float d0 = v[j] - mean; q += d0 * d0; }
            q += __shfl_xor(q, 1); q += __shfl_xor(q, 2);
            q += __shfl_xor(q, 4); q += __shfl_xor(q, 8);
            float rstd = rsqrtf(q * (1.f / 64.f) + 1e-5f);
            const int row = ((o0 + obs) * 5 + tq) * 64;
            #pragma unroll
            for (int j = 0; j < 4; ++j) {
                int c = l16 * 4 + j;
                xo[row + c] = (v[j] - mean) * rstd * g1[c] + be1[c];
            }
        }
    }
}

// ---------------------------------------------------------------------------
// Fallback attention (pure VALU)
// ---------------------------------------------------------------------------
__global__ __launch_bounds__(NT) void k_att(
    float* __restrict__ x,
    const float* __restrict__ wqkv, const float* __restrict__ bqkv,
    const float* __restrict__ wo, const float* __restrict__ bo,
    const float* __restrict__ g1, const float* __restrict__ be1)
{
    const int b = blockIdx.x;
    const int tid = threadIdx.x;
    __shared__ float xs[5][64];
    __shared__ float qkv[5][192];
    __shared__ float att[4][5][5];
    __shared__ float os[5][64];
    __shared__ float xr[5][64];
    __shared__ float stat[5][2];

    for (int i = tid; i < 320; i += NT) xs[i >> 6][i & 63] = x[b * 320 + i];
    __syncthreads();

    for (int i = tid; i < 960; i += NT) {
        int p = i / 192, j = i % 192;
        float s = bqkv[j];
        const float* wr = wqkv + j * 64;
        const float* xm = xs[p];
        #pragma unroll
        for (int k = 0; k < 64; ++k) s += xm[k] * wr[k];
        qkv[p][j] = s;
    }
    __syncthreads();

    if (tid < 100) {
        int h = tid / 25, r = tid % 25, q = r / 5, kk = r % 5;
        float s = 0.f;
        #pragma unroll
        for (int d = 0; d < 16; ++d) s += qkv[q][h * 16 + d] * qkv[kk][64 + h * 16 + d];
        att[h][q][kk] = s * 0.25f;
    }
    __syncthreads();

    if (tid < 20) {
        int h = tid / 5, q = tid % 5;
        float m = att[h][q][0];
        for (int k = 1; k < 5; ++k) m = fmaxf(m, att[h][q][k]);
        float sum = 0.f;
        for (int k = 0; k < 5; ++k) { float e = expf(att[h][q][k] - m); att[h][q][k] = e; sum += e; }
        float inv = 1.f / sum;
        for (int k = 0; k < 5; ++k) att[h][q][k] *= inv;
    }
    __syncthreads();

    for (int i = tid; i < 320; i += NT) {
        int p = i >> 6, c = i & 63, h = c >> 4;
        float s = 0.f;
        #pragma unroll
        for (int k = 0; k < 5; ++k) s += att[h][p][k] * qkv[k][128 + c];
        os[p][c] = s;
    }
    __syncthreads();

    for (int i = tid; i < 320; i += NT) {
        int p = i >> 6, c = i & 63;
        float s = bo[c];
        const float* wr = wo + c * 64;
        const float* om = os[p];
        #pragma unroll
        for (int k = 0; k < 64; ++k) s += om[k] * wr[k];
        xr[p][c] = xs[p][c] + s;
    }
    __syncthreads();

    if (tid < 5) {
        float m = 0.f;
        for (int k = 0; k < 64; ++k) m += xr[tid][k];
        m *= (1.f / 64.f);
        float v = 0.f;
        for (int k = 0; k < 64; ++k) { float d = xr[tid][k] - m; v += d * d; }
        v *= (1.f / 64.f);
        stat[tid][0] = m;
        stat[tid][1] = 1.f / sqrtf(v + 1e-5f);
    }
    __syncthreads();

    for (int i = tid; i < 320; i += NT) {
        int p = i >> 6, c = i & 63;
        x[b * 320 + i] = (xr[p][c] - stat[p][0]) * stat[p][1] * g1[c] + be1[c];
    }
}

// ---------------------------------------------------------------------------
// Kernel 3 (MFMA, wave-split hidden, zero-barrier L2 streaming) - R11, proven
// ---------------------------------------------------------------------------
#define PKCH 8192
__global__ __launch_bounds__(256, 2) void k_ffn8(
    float* __restrict__ x,
    const unsigned short* __restrict__ wpk,
    const float* __restrict__ b1,
    const float* __restrict__ b2,
    const float* __restrict__ g2, const float* __restrict__ be2)
{
    __shared__ float red[4][4][4][64][4];
    const int tid  = threadIdx.x;
    const int lane = tid & 63;
    const int wid  = tid >> 6;
    const int lr = lane & 15;
    const int lg = lane >> 4;
    const int row0 = blockIdx.x * 64;

    bf16x8 bx[4][2];
    #pragma unroll
    for (int mf = 0; mf < 4; ++mf)
        #pragma unroll
        for (int kk = 0; kk < 2; ++kk) {
            const float* p = x + (row0 + mf * 16 + lr) * 64 + kk * 32 + lg * 8;
            f32x4 aa = *(const f32x4*)(p);
            f32x4 bb = *(const f32x4*)(p + 4);
            bx[mf][kk] = pk_bf16x8(aa, bb);
        }

    f32x4 acc[4][4] = {};
    const int fbase = (lg * 16 + lr) * 8;
    const unsigned short* wp = wpk + (wid * 8) * PKCH;
    const float* b1w = b1 + wid * 512;

    for (int c = 0; c < 8; ++c) {
        const unsigned short* L = wp + c * PKCH;
        bf16x8 rA[4], rB[4], rC[4], rD[4];
        #pragma unroll
        for (int hc = 0; hc < 4; ++hc) {
            rA[hc] = *(const bf16x8*)&L[hc * 512 + fbase];
            rB[hc] = *(const bf16x8*)&L[2048 + hc * 512 + fbase];
            rC[hc] = *(const bf16x8*)&L[4096 + hc * 512 + fbase];
            rD[hc] = *(const bf16x8*)&L[6144 + hc * 512 + fbase];
        }
        f32x4 b1v[4];
        #pragma unroll
        for (int hc = 0; hc < 4; ++hc)
            b1v[hc] = *(const f32x4*)(b1w + c * 64 + hc * 16 + lg * 4);

        #pragma unroll
        for (int hc = 0; hc < 4; ++hc) {
            #pragma unroll
            for (int mf = 0; mf < 4; ++mf) {
                f32x4 d = MFMA16x32(rA[hc], bx[mf][0], b1v[hc]);
                d = MFMA16x32(rB[hc], bx[mf][1], d);
                #pragma unroll
                for (int r = 0; r < 4; ++r) d[r] = fmaxf(d[r], 0.f);
                bf16x4 h = pk_bf16(d);
                acc[mf][0] = mfma16x16(h, lo4(rC[hc]), acc[mf][0]);
                acc[mf][1] = mfma16x16(h, hi4(rC[hc]), acc[mf][1]);
                acc[mf][2] = mfma16x16(h, lo4(rD[hc]), acc[mf][2]);
                acc[mf][3] = mfma16x16(h, hi4(rD[hc]), acc[mf][3]);
            }
        }
    }

    #pragma unroll
    for (int mf = 0; mf < 4; ++mf)
        #pragma unroll
        for (int nf = 0; nf < 4; ++nf)
            *(f32x4*)&red[wid][mf][nf][lane][0] = acc[mf][nf];
    __syncthreads();

    f32x4 vr[4];
    #pragma unroll
    for (int nf = 0; nf < 4; ++nf) {
        f32x4 s0 = *(const f32x4*)&red[0][wid][nf][lane][0];
        f32x4 s1 = *(const f32x4*)&red[1][wid][nf][lane][0];
        f32x4 s2 = *(const f32x4*)&red[2][wid][nf][lane][0];
        f32x4 s3 = *(const f32x4*)&red[3][wid][nf][lane][0];
        vr[nf] = (s0 + s1) + (s2 + s3);
    }

    #pragma unroll
    for (int r = 0; r < 4; ++r) {
        const int m = row0 + wid * 16 + lg * 4 + r;
        float v[4];
        float s = 0.f;
        #pragma unroll
        for (int nf = 0; nf < 4; ++nf) {
            int cc = nf * 16 + lr;
            float y = vr[nf][r] + b2[cc] + x[m * 64 + cc];
            v[nf] = y; s += y;
        }
        s += __shfl_xor(s, 1); s += __shfl_xor(s, 2);
        s += __shfl_xor(s, 4); s += __shfl_xor(s, 8);
        float mean = s * (1.f / 64.f);
        float q = 0.f;
        #pragma unroll
        for (int nf = 0; nf < 4; ++nf) { float d0 = v[nf] - mean; q += d0 * d0; }
        q += __shfl_xor(q, 1); q += __shfl_xor(q, 2);
        q += __shfl_xor(q, 4); q += __shfl_xor(q, 8);
        float rstd = rsqrtf(q * (1.f / 64.f) + 1e-5f);
        #pragma unroll
        for (int nf = 0; nf < 4; ++nf) {
            int cc = nf * 16 + lr;
            x[m * 64 + cc] = (v[nf] - mean) * rstd * g2[cc] + be2[cc];
        }
    }
}

// ---------------------------------------------------------------------------
// Fallback FFN (pure VALU)
// ---------------------------------------------------------------------------
#define GRP 8
#define ROWS (GRP * 5)
__global__ __launch_bounds__(NT) void k_ffn(
    float* __restrict__ x,
    const float* __restrict__ w1, const float* __restrict__ b1,
    const float* __restrict__ w2, const float* __restrict__ b2,
    const float* __restrict__ g2, const float* __restrict__ be2)
{
    const int tid = threadIdx.x;
    const int base = blockIdx.x * (ROWS * 64);
    __shared__ float xs[ROWS][64];
    __shared__ float hch[ROWS][128];
    __shared__ float stat[ROWS][2];

    for (int i = tid; i < ROWS * 64; i += NT) xs[i >> 6][i & 63] = x[base + i];
    __syncthreads();

    const int c = tid & 63;
    const int g = tid >> 6;
    float acc[10];
    #pragma unroll
    for (int r = 0; r < 10; ++r) acc[r] = 0.f;

    for (int ch = 0; ch < 16; ++ch) {
        for (int ii = tid; ii < ROWS * 128; ii += NT) {
            int m = ii >> 7, j = ii & 127;
            int jj = (ch << 7) + j;
            float s = b1[jj];
            const float* wr = w1 + jj * 64;
            const float* xm = xs[m];
            #pragma unroll
            for (int k = 0; k < 64; ++k) s += xm[k] * wr[k];
            hch[m][j] = fmaxf(s, 0.f);
        }
        __syncthreads();
        const float* w2r = w2 + c * 2048 + (ch << 7);
        for (int j = 0; j < 128; ++j) {
            float wv = w2r[j];
            #pragma unroll
            for (int r = 0; r < 10; ++r) acc[r] += hch[g * 10 + r][j] * wv;
        }
        __syncthreads();
    }

    #pragma unroll
    for (int r = 0; r < 10; ++r) {
        int m = g * 10 + r;
        hch[m][c] = acc[r] + b2[c] + xs[m][c];
    }
    __syncthreads();

    if (tid < ROWS) {
        float m = 0.f;
        for (int k = 0; k < 64; ++k) m += hch[tid][k];
        m *= (1.f / 64.f);
        float v = 0.f;
        for (int k = 0; k < 64; ++k) { float d = hch[tid][k] - m; v += d * d; }
        v *= (1.f / 64.f);
        stat[tid][0] = m;
        stat[tid][1] = 1.f / sqrtf(v + 1e-5f);
    }
    __syncthreads();

    for (int i = tid; i < ROWS * 64; i += NT) {
        int m = i >> 6, cc = i & 63;
        x[base + i] = (hch[m][cc] - stat[m][0]) * stat[m][1] * g2[cc] + be2[cc];
    }
}

// ---------------------------------------------------------------------------
extern "C" void kernel_launch(void* const* d_in, const int* in_sizes, int n_in,
                              void* d_out, int out_size, void* d_ws, size_t ws_size,
                              hipStream_t stream)
{
    (void)in_sizes; (void)n_in; (void)out_size;
    const int*   ai       = (const int*)d_in[0];
    const int*   aj       = (const int*)d_in[1];
    const int*   gi       = (const int*)d_in[2];
    const int*   gj       = (const int*)d_in[3];
    const int*   walls    = (const int*)d_in[4];
    const float* mlp_w1   = (const float*)d_in[5];
    const float* mlp_b1   = (const float*)d_in[6];
    const float* mlp_w2   = (const float*)d_in[7];
    const float* mlp_b2   = (const float*)d_in[8];
    const float* in_proj_w = (const float*)d_in[9];
    const float* in_proj_b = (const float*)d_in[10];
    const float* out_w    = (const float*)d_in[11];
    const float* out_b    = (const float*)d_in[12];
    const float* ln1_g    = (const float*)d_in[13];
    const float* ln1_b    = (const float*)d_in[14];
    const float* ln2_g    = (const float*)d_in[15];
    const float* ln2_b    = (const float*)d_in[16];
    const float* ffn_w1   = (const float*)d_in[17];
    const float* ffn_b1   = (const float*)d_in[18];
    const float* ffn_w2   = (const float*)d_in[19];
    const float* ffn_b2   = (const float*)d_in[20];

    float* x = (float*)d_out;
    const int B = 8192;
    const bool fast  = ws_size >= (size_t)(WS_BASE * 2);
    const bool fast2 = ws_size >= (size_t)(WS_TOTAL * 2);
    unsigned short* wsbf = (unsigned short*)d_ws;

    if (fast)
        k_cvtw<<<2048, NT, 0, stream>>>(ffn_w1, ffn_w2, in_proj_w, out_w,
                                        mlp_w1, mlp_w2, fast2 ? 1 : 0, wsbf);

    if (fast2) {
        k_feat2<<<B / FB, 320, 0, stream>>>(ai, aj, gi, gj, walls,
            wsbf + WS_MW1, mlp_b1, wsbf + WS_MW2, mlp_b2, x);
    } else {
        k_feat<<<B, NT, 0, stream>>>(ai, aj, gi, gj, walls,
                                     mlp_w1, mlp_b1, mlp_w2, mlp_b2, x);
    }

    for (int l = 0; l < 2; ++l) {
        if (fast) {
            k_att3<<<512, 256, 0, stream>>>(x, x,
                wsbf + WS_QKV + l * 12288, in_proj_b + l * 192,
                wsbf + WS_WO + l * 4096, out_b + l * 64,
                ln1_g + l * 64, ln1_b + l * 64);
            k_ffn8<<<640, 256, 0, stream>>>(x,
                wsbf + WS_FPK + l * 262144, ffn_b1 + l * 2048,
                ffn_b2 + l * 64,
                ln2_g + l * 64, ln2_b + l * 64);
        } else {
            k_att<<<B, NT, 0, stream>>>(x,
                in_proj_w + l * 192 * 64, in_proj_b + l * 192,
                out_w + l * 64 * 64, out_b + l * 64,
                ln1_g + l * 64, ln1_b + l * 64);
            k_ffn<<<B / GRP, NT, 0, stream>>>(x,
                ffn_w1 + l * 2048 * 64, ffn_b1 + l * 2048,
                ffn_w2 + l * 64 * 2048, ffn_b2 + l * 64,
                ln2_g + l * 64, ln2_b + l * 64);
        }
    }
}

// Round 18
// 148.644 us; speedup vs baseline: 1.2151x; 1.0033x over previous
//
#include <hip/hip_runtime.h>
#include <math.h>

#define NT 256

typedef __attribute__((ext_vector_type(4))) float  f32x4;
typedef __attribute__((ext_vector_type(8))) short  bf16x8;
typedef __attribute__((ext_vector_type(4))) short  bf16x4;

static __device__ __forceinline__ short f2bf(float f) {
    unsigned u = __builtin_bit_cast(unsigned, f);
    unsigned r = (u + 0x7fffu + ((u >> 16) & 1u)) >> 16;
    return (short)r;
}

// round-to-nearest-even bf16 pair-pack, pure VALU (no asm, no union).
// NOTE: v_cvt_pk_bf16_f32 inline asm produced NaN under this hipcc in BOTH
// union-pun (R5) and direct-output (R16) forms -- banned for this session.
static __device__ __forceinline__ unsigned pk2(float a, float b) {
    unsigned ua = __builtin_bit_cast(unsigned, a);
    unsigned ub = __builtin_bit_cast(unsigned, b);
    ua = (ua + 0x7fffu + ((ua >> 16) & 1u)) >> 16;
    ub = (ub + 0x7fffu + ((ub >> 16) & 1u)) & 0xffff0000u;
    return ua | ub;
}
static __device__ __forceinline__ bf16x4 pk_bf16(f32x4 d) {
    uint2 t;
    t.x = pk2(d[0], d[1]);
    t.y = pk2(d[2], d[3]);
    return __builtin_bit_cast(bf16x4, t);
}
static __device__ __forceinline__ bf16x8 pk_bf16x8(f32x4 a, f32x4 b) {
    uint4 t;
    t.x = pk2(a[0], a[1]);
    t.y = pk2(a[2], a[3]);
    t.z = pk2(b[0], b[1]);
    t.w = pk2(b[2], b[3]);
    return __builtin_bit_cast(bf16x8, t);
}
static __device__ __forceinline__ bf16x4 lo4(bf16x8 v) {
    return __builtin_shufflevector(v, v, 0, 1, 2, 3);
}
static __device__ __forceinline__ bf16x4 hi4(bf16x8 v) {
    return __builtin_shufflevector(v, v, 4, 5, 6, 7);
}

#define MFMA16x32(a, b, c) __builtin_amdgcn_mfma_f32_16x16x32_bf16(a, b, c, 0, 0, 0)

#if __has_builtin(__builtin_amdgcn_mfma_f32_16x16x16bf16_1k)
static __device__ __forceinline__ f32x4 mfma16x16(bf16x4 a, bf16x4 b, f32x4 c) {
    return __builtin_amdgcn_mfma_f32_16x16x16bf16_1k(a, b, c, 0, 0, 0);
}
#elif __has_builtin(__builtin_amdgcn_mfma_f32_16x16x16_bf16)
static __device__ __forceinline__ f32x4 mfma16x16(bf16x4 a, bf16x4 b, f32x4 c) {
    return __builtin_amdgcn_mfma_f32_16x16x16_bf16(a, b, c, 0, 0, 0);
}
#else
static __device__ __forceinline__ f32x4 mfma16x16(bf16x4 a, bf16x4 b, f32x4 c) {
    f32x4 d;
    asm("v_mfma_f32_16x16x16_bf16 %0, %1, %2, %3" : "=v"(d) : "v"(a), "v"(b), "v"(c));
    return d;
}
#endif

// ws layout (units: unsigned short):
// WS_FPK: packed FFN weights, chunk-major fragment order, [2 layers][32 chunks][8192]
//   per chunk: region A(2048)=W1 cols 0..31 frag-order, B(2048)=W1 cols 32..63,
//              C(2048)=W2 nf0/1, D(2048)=W2 nf2/3.  lane = hc*64+lg*16+lr, j=0..7.
#define WS_FPK  0           // (524288)
#define WS_QKV  524288      // in_proj_w [2][192][64]  (24576)
#define WS_WO   548864      // out_w [2][64][64]       (8192)
#define WS_BASE 557056
#define WS_MW1  557056      // mlp_w1 padded [128][64] (8192)
#define WS_MW2  565248      // mlp_w2 [64][128]        (8192)
#define WS_TOTAL 573440

// ---------------------------------------------------------------------------
// Kernel 0: convert + pack weights to bf16 in d_ws (R11/R12 unpaired layout)
// ---------------------------------------------------------------------------
__global__ __launch_bounds__(NT) void k_cvtw(
    const float* __restrict__ ffn_w1, const float* __restrict__ ffn_w2,
    const float* __restrict__ in_proj_w, const float* __restrict__ out_w,
    const float* __restrict__ mlp_w1, const float* __restrict__ mlp_w2,
    int do_mlp,
    unsigned short* __restrict__ ws)
{
    int i = blockIdx.x * NT + threadIdx.x;
    if (i < 524288) {
        int l = i >> 18;
        int w = i & 262143;
        int c = w >> 13;
        int ww = w & 8191;
        int region = ww >> 11;
        int q = ww & 2047;
        int lane = q >> 3, j = q & 7;
        int hc = lane >> 6, lg = (lane >> 4) & 3, lr = lane & 15;
        const float* W1 = ffn_w1 + l * 131072;   // [2048][64]
        const float* W2 = ffn_w2 + l * 131072;   // [64][2048]
        float v;
        if (region == 0)
            v = W1[(c * 64 + hc * 16 + lr) * 64 + lg * 8 + j];
        else if (region == 1)
            v = W1[(c * 64 + hc * 16 + lr) * 64 + 32 + lg * 8 + j];
        else {
            int nf = ((region - 2) << 1) + (j >> 2);
            int r = j & 3;
            v = W2[(nf * 16 + lr) * 2048 + c * 64 + hc * 16 + lg * 4 + r];
        }
        ws[WS_FPK + i] = (unsigned short)f2bf(v);
    }
    if (i < 24576) ws[WS_QKV + i] = (unsigned short)f2bf(in_proj_w[i]);
    if (i < 8192)  ws[WS_WO + i]  = (unsigned short)f2bf(out_w[i]);
    if (do_mlp && i < 8192) {
        int row = i >> 6, col = i & 63;
        ws[WS_MW1 + i] = (col < 55) ? (unsigned short)f2bf(mlp_w1[row * 55 + col]) : 0;
        ws[WS_MW2 + i] = (unsigned short)f2bf(mlp_w2[i]);
    }
}

// ---------------------------------------------------------------------------
// Kernel 1 (MFMA): features + feat MLP (unchanged from R3)
// ---------------------------------------------------------------------------
#define FB 16
__global__ __launch_bounds__(320) void k_feat2(
    const int* __restrict__ ai, const int* __restrict__ aj,
    const int* __restrict__ gi, const int* __restrict__ gj,
    const int* __restrict__ walls,
    const unsigned short* __restrict__ w1p,
    const float* __restrict__ b1,
    const unsigned short* __restrict__ w2p,
    const float* __restrict__ b2,
    float* __restrict__ x)
{
    const int tid = threadIdx.x;
    const int ob0 = blockIdx.x * FB;
    __shared__ unsigned char wl[FB * 256];
    __shared__ short fe[80][72];
    __shared__ int t3s[FB][3];

    for (int i = tid; i < FB * 256; i += 320)
        wl[i] = (unsigned char)walls[ob0 * 256 + i];
    __syncthreads();

    const int lane = tid & 63;
    const int wid  = tid >> 6;

    if (wid < 4) {
        #pragma unroll
        for (int q = 0; q < 4; ++q) {
            const int o = wid * 4 + q;
            const unsigned char* wp = wl + o * 256 + lane * 4;
            int m = (wp[0] ? 1 : 0) | (wp[1] ? 2 : 0) | (wp[2] ? 4 : 0) | (wp[3] ? 8 : 0);
            unsigned long long bm[4];
            bm[0] = __ballot(m & 1); bm[1] = __ballot(m & 2);
            bm[2] = __ballot(m & 4); bm[3] = __ballot(m & 8);
            int res[3];
            #pragma unroll
            for (int c = 0; c < 3; ++c) {
                int best = 1 << 30, bj = -1;
                #pragma unroll
                for (int j = 0; j < 4; ++j)
                    if (bm[j]) {
                        int cand = 4 * (int)__builtin_ctzll(bm[j]) + j;
                        if (cand < best) { best = cand; bj = j; }
                    }
                res[c] = (bj >= 0) ? best : 256;
                if (bj >= 0) bm[bj] &= bm[bj] - 1;
            }
            if (lane == 0) {
                t3s[o][0] = res[0]; t3s[o][1] = res[1]; t3s[o][2] = res[2];
            }
        }
    }
    __syncthreads();

    if (tid < 80) {
        const int o = tid / 5, tq = tid % 5;
        const int gob = ob0 + o;
        const unsigned char* wp = wl + o * 256;
        const int mi[5] = {0, -1, 1, 0, 0};
        const int mj[5] = {0, 0, 0, -1, 1};
        const int a_i = ai[gob], a_j = aj[gob];
        int ni = a_i + mi[tq], nj = a_j + mj[tq];
        bool inb = (ni >= 0 && ni < 16 && nj >= 0 && nj < 16);
        int pi = inb ? ni : a_i;
        int pj = inb ? nj : a_j;

        float f[64];
        #pragma unroll
        for (int d = 55; d < 64; ++d) f[d] = 0.f;

        const float ain = 2.f * (float)pi / 15.f - 1.f;
        const float ajn = 2.f * (float)pj / 15.f - 1.f;
        const float gin = 2.f * (float)gi[gob] / 15.f - 1.f;
        const float gjn = 2.f * (float)gj[gob] / 15.f - 1.f;
        const float dxg = gjn - ajn, dyg = gin - ain;
        const float dg = sqrtf(dxg * dxg + dyg * dyg + 1e-8f);
        f[0] = ain; f[1] = ajn; f[2] = gin; f[3] = gjn;
        f[4] = dxg; f[5] = dyg; f[6] = dg; f[7] = dyg / dg; f[8] = dxg / dg;

        #pragma unroll
        for (int w = 0; w < 3; ++w) {
            int idx = t3s[o][w];
            float vm = (idx < 256) ? 1.f : 0.f;
            int safe = (idx < 256) ? idx : 0;
            float win = 2.f * (float)(safe >> 4) / 15.f - 1.f;
            float wjn = 2.f * (float)(safe & 15) / 15.f - 1.f;
            {
                float dx = wjn - ajn, dy = win - ain;
                float d = sqrtf(dx * dx + dy * dy + 1e-8f);
                f[9 + w * 7 + 0] = win * vm; f[9 + w * 7 + 1] = wjn * vm;
                f[9 + w * 7 + 2] = dx * vm;  f[9 + w * 7 + 3] = dy * vm;
                f[9 + w * 7 + 4] = d * vm;
                f[9 + w * 7 + 5] = (dy / d) * vm; f[9 + w * 7 + 6] = (dx / d) * vm;
            }
            {
                float dx = wjn - gjn, dy = win - gin;
                float d = sqrtf(dx * dx + dy * dy + 1e-8f);
                f[30 + w * 7 + 0] = win * vm; f[30 + w * 7 + 1] = wjn * vm;
                f[30 + w * 7 + 2] = dx * vm;  f[30 + w * 7 + 3] = dy * vm;
                f[30 + w * 7 + 4] = d * vm;
                f[30 + w * 7 + 5] = (dy / d) * vm; f[30 + w * 7 + 6] = (dx / d) * vm;
            }
        }
        f[51] = (pi > 0)  ? (float)wp[(pi - 1) * 16 + pj] : 1.f;
        f[52] = (pi < 15) ? (float)wp[(pi + 1) * 16 + pj] : 1.f;
        f[53] = (pj > 0)  ? (float)wp[pi * 16 + (pj - 1)] : 1.f;
        f[54] = (pj < 15) ? (float)wp[pi * 16 + (pj + 1)] : 1.f;

        unsigned* dst = (unsigned*)&fe[tid][0];
        #pragma unroll
        for (int d = 0; d < 32; ++d)
            dst[d] = pk2(f[2 * d], f[2 * d + 1]);
    }
    __syncthreads();

    const int lr = lane & 15;
    const int lg = lane >> 4;
    const int t0 = wid * 16;

    bf16x8 bf0 = *(const bf16x8*)&fe[t0 + lr][lg * 8];
    bf16x8 bf1 = *(const bf16x8*)&fe[t0 + lr][32 + lg * 8];

    f32x4 acc[4] = {};
    #pragma unroll
    for (int hc = 0; hc < 8; ++hc) {
        bf16x8 a0 = *(const bf16x8*)(w1p + (hc * 16 + lr) * 64 + lg * 8);
        bf16x8 a1 = *(const bf16x8*)(w1p + (hc * 16 + lr) * 64 + 32 + lg * 8);
        f32x4 d = {0.f, 0.f, 0.f, 0.f};
        d = MFMA16x32(a0, bf0, d);
        d = MFMA16x32(a1, bf1, d);
        f32x4 b1v = *(const f32x4*)(b1 + hc * 16 + lg * 4);
        bf16x4 h;
        #pragma unroll
        for (int r = 0; r < 4; ++r) {
            float s = d[r] + b1v[r];
            h[r] = f2bf(0.5f * s * (1.f + erff(s * 0.70710678118654752f)));
        }
        #pragma unroll
        for (int nf = 0; nf < 4; ++nf) {
            bf16x4 bw = *(const bf16x4*)(w2p + (nf * 16 + lr) * 128 + hc * 16 + lg * 4);
            acc[nf] = mfma16x16(h, bw, acc[nf]);
        }
    }

    const int gt0 = blockIdx.x * 80 + t0;
    #pragma unroll
    for (int r = 0; r < 4; ++r) {
        const int row = (gt0 + lg * 4 + r) * 64;
        #pragma unroll
        for (int nf = 0; nf < 4; ++nf)
            x[row + nf * 16 + lr] = acc[nf][r] + b2[nf * 16 + lr];
    }
}

// ---------------------------------------------------------------------------
// Fallback kernel 1 (pure VALU)
// ---------------------------------------------------------------------------
__global__ __launch_bounds__(NT) void k_feat(
    const int* __restrict__ ai, const int* __restrict__ aj,
    const int* __restrict__ gi, const int* __restrict__ gj,
    const int* __restrict__ walls,
    const float* __restrict__ w1, const float* __restrict__ b1,
    const float* __restrict__ w2, const float* __restrict__ b2,
    float* __restrict__ xout)
{
    const int b = blockIdx.x;
    const int tid = threadIdx.x;
    __shared__ float wallf[256];
    __shared__ unsigned long long wmask[4];
    __shared__ int   t3[3];
    __shared__ float feats[5][55];
    __shared__ float h1[5][128];

    int wv = walls[b * 256 + tid];
    wallf[tid] = (float)wv;
    unsigned long long bm = __ballot(wv == 1);
    if ((tid & 63) == 0) wmask[tid >> 6] = bm;
    __syncthreads();

    if (tid == 0) {
        int c = 0;
        for (int w = 0; w < 4 && c < 3; ++w) {
            unsigned long long mm = wmask[w];
            while (mm && c < 3) {
                t3[c++] = w * 64 + __builtin_ctzll(mm);
                mm &= mm - 1;
            }
        }
        for (; c < 3; ++c) t3[c] = 256;
    }
    __syncthreads();

    if (tid < 5) {
        const int mi[5] = {0, -1, 1, 0, 0};
        const int mj[5] = {0, 0, 0, -1, 1};
        const int a_i = ai[b], a_j = aj[b];
        int ni = a_i + mi[tid], nj = a_j + mj[tid];
        bool inb = (ni >= 0 && ni < 16 && nj >= 0 && nj < 16);
        int pi = inb ? ni : a_i;
        int pj = inb ? nj : a_j;

        const float ain = 2.f * (float)pi / 15.f - 1.f;
        const float ajn = 2.f * (float)pj / 15.f - 1.f;
        const float gin = 2.f * (float)gi[b] / 15.f - 1.f;
        const float gjn = 2.f * (float)gj[b] / 15.f - 1.f;
        const float dxg = gjn - ajn, dyg = gin - ain;
        const float dg = sqrtf(dxg * dxg + dyg * dyg + 1e-8f);

        float* f = feats[tid];
        f[0] = ain; f[1] = ajn; f[2] = gin; f[3] = gjn;
        f[4] = dxg; f[5] = dyg; f[6] = dg; f[7] = dyg / dg; f[8] = dxg / dg;

        for (int w = 0; w < 3; ++w) {
            int idx = t3[w];
            float vm = (idx < 256) ? 1.f : 0.f;
            int safe = (idx < 256) ? idx : 0;
            float win = 2.f * (float)(safe >> 4) / 15.f - 1.f;
            float wjn = 2.f * (float)(safe & 15) / 15.f - 1.f;
            {
                float dx = wjn - ajn, dy = win - ain;
                float d = sqrtf(dx * dx + dy * dy + 1e-8f);
                float* o = f + 9 + w * 7;
                o[0] = win * vm; o[1] = wjn * vm; o[2] = dx * vm; o[3] = dy * vm;
                o[4] = d * vm;  o[5] = (dy / d) * vm; o[6] = (dx / d) * vm;
            }
            {
                float dx = wjn - gjn, dy = win - gin;
                float d = sqrtf(dx * dx + dy * dy + 1e-8f);
                float* o = f + 30 + w * 7;
                o[0] = win * vm; o[1] = wjn * vm; o[2] = dx * vm; o[3] = dy * vm;
                o[4] = d * vm;  o[5] = (dy / d) * vm; o[6] = (dx / d) * vm;
            }
        }
        f[51] = (pi > 0)  ? wallf[(pi - 1) * 16 + pj] : 1.f;
        f[52] = (pi < 15) ? wallf[(pi + 1) * 16 + pj] : 1.f;
        f[53] = (pj > 0)  ? wallf[pi * 16 + (pj - 1)] : 1.f;
        f[54] = (pj < 15) ? wallf[pi * 16 + (pj + 1)] : 1.f;
    }
    __syncthreads();

    for (int i = tid; i < 640; i += NT) {
        int p = i >> 7, j = i & 127;
        float s = b1[j];
        const float* wr = w1 + j * 55;
        const float* fp = feats[p];
        #pragma unroll
        for (int k = 0; k < 55; ++k) s += fp[k] * wr[k];
        h1[p][j] = 0.5f * s * (1.f + erff(s * 0.70710678118654752f));
    }
    __syncthreads();

    for (int i = tid; i < 320; i += NT) {
        int p = i >> 6, j = i & 63;
        float s = b2[j];
        const float* wr = w2 + j * 128;
        #pragma unroll
        for (int k = 0; k < 128; ++k) s += h1[p][k] * wr[k];
        xout[b * 320 + i] = s;
    }
}

// ---------------------------------------------------------------------------
// Kernel 2 (MFMA, head-per-wave): MHA + residual + LN1 (R12, proven)
// ---------------------------------------------------------------------------
__global__ __launch_bounds__(256, 2) void k_att3(
    const float* __restrict__ x, float* __restrict__ xo,
    const unsigned short* __restrict__ wqkv,
    const float* __restrict__ bqkv,
    const unsigned short* __restrict__ wo,
    const float* __restrict__ bo,
    const float* __restrict__ g1, const float* __restrict__ be1)
{
    const int tid  = threadIdx.x;
    const int lane = tid & 63;
    const int wid  = tid >> 6;
    const int lr = lane & 15;
    const int lg = lane >> 4;
    const int o0 = blockIdx.x * 16;

    __shared__ unsigned short o_sh[5][16][68];
    __shared__ float          y_sh[5][16][68];

    bf16x8 bx[5][2];
    #pragma unroll
    for (int tq = 0; tq < 5; ++tq)
        #pragma unroll
        for (int kf = 0; kf < 2; ++kf) {
            const float* p = x + ((o0 + lr) * 5 + tq) * 64 + kf * 32 + lg * 8;
            f32x4 aa = *(const f32x4*)(p);
            f32x4 bb = *(const f32x4*)(p + 4);
            bx[tq][kf] = pk_bf16x8(aa, bb);
        }

    {
        const int h = wid;
        bf16x8 aq[2], ak[2], av[2];
        #pragma unroll
        for (int kf = 0; kf < 2; ++kf) {
            aq[kf] = *(const bf16x8*)(wqkv + (h * 16 + lr) * 64 + kf * 32 + lg * 8);
            ak[kf] = *(const bf16x8*)(wqkv + (64 + h * 16 + lr) * 64 + kf * 32 + lg * 8);
            av[kf] = *(const bf16x8*)(wqkv + (128 + h * 16 + lr) * 64 + kf * 32 + lg * 8);
        }
        f32x4 bq = *(const f32x4*)(bqkv + h * 16 + lg * 4);
        f32x4 bk = *(const f32x4*)(bqkv + 64 + h * 16 + lg * 4);
        f32x4 bv = *(const f32x4*)(bqkv + 128 + h * 16 + lg * 4);

        f32x4 qf[5], kf_[5], vf[5];
        #pragma unroll
        for (int t = 0; t < 5; ++t) {
            f32x4 d = {0.f, 0.f, 0.f, 0.f};
            d = MFMA16x32(aq[0], bx[t][0], d);
            d = MFMA16x32(aq[1], bx[t][1], d);
            qf[t] = d + bq;
            f32x4 e = {0.f, 0.f, 0.f, 0.f};
            e = MFMA16x32(ak[0], bx[t][0], e);
            e = MFMA16x32(ak[1], bx[t][1], e);
            kf_[t] = e + bk;
            f32x4 g = {0.f, 0.f, 0.f, 0.f};
            g = MFMA16x32(av[0], bx[t][0], g);
            g = MFMA16x32(av[1], bx[t][1], g);
            vf[t] = g + bv;
        }

        float p_[5][5];
        #pragma unroll
        for (int tq = 0; tq < 5; ++tq)
            #pragma unroll
            for (int tk = 0; tk < 5; ++tk) {
                float s = qf[tq][0] * kf_[tk][0] + qf[tq][1] * kf_[tk][1]
                        + qf[tq][2] * kf_[tk][2] + qf[tq][3] * kf_[tk][3];
                s += __shfl_xor(s, 16);
                s += __shfl_xor(s, 32);
                p_[tq][tk] = s * 0.25f;
            }
        #pragma unroll
        for (int tq = 0; tq < 5; ++tq) {
            float m = p_[tq][0];
            #pragma unroll
            for (int tk = 1; tk < 5; ++tk) m = fmaxf(m, p_[tq][tk]);
            float sum = 0.f;
            #pragma unroll
            for (int tk = 0; tk < 5; ++tk) {
                float e = __expf(p_[tq][tk] - m);
                p_[tq][tk] = e; sum += e;
            }
            float inv = 1.f / sum;
            #pragma unroll
            for (int tk = 0; tk < 5; ++tk) p_[tq][tk] *= inv;
        }

        #pragma unroll
        for (int tq = 0; tq < 5; ++tq) {
            f32x4 o = {0.f, 0.f, 0.f, 0.f};
            #pragma unroll
            for (int tk = 0; tk < 5; ++tk) o += p_[tq][tk] * vf[tk];
            *(bf16x4*)&o_sh[tq][lr][h * 16 + lg * 4] = pk_bf16(o);
        }
    }
    __syncthreads();

    {
        bf16x4 bwo[4];
        #pragma unroll
        for (int kf = 0; kf < 4; ++kf)
            bwo[kf] = *(const bf16x4*)(wo + (wid * 16 + lr) * 64 + kf * 16 + lg * 4);

        #pragma unroll
        for (int tq = 0; tq < 5; ++tq) {
            f32x4 acc = {0.f, 0.f, 0.f, 0.f};
            #pragma unroll
            for (int kf = 0; kf < 4; ++kf) {
                bf16x4 a2 = *(const bf16x4*)&o_sh[tq][lr][kf * 16 + lg * 4];
                acc = mfma16x16(a2, bwo[kf], acc);
            }
            const int col = wid * 16 + lr;
            const float bv2 = bo[col];
            #pragma unroll
            for (int r = 0; r < 4; ++r) {
                const int obs = lg * 4 + r;
                y_sh[tq][obs][col] =
                    acc[r] + bv2 + x[((o0 + obs) * 5 + tq) * 64 + col];
            }
        }
    }
    __syncthreads();

    {
        const int grp = tid >> 4;
        const int l16 = tid & 15;
        #pragma unroll
        for (int it = 0; it < 5; ++it) {
            const int tq = it, obs = grp;
            f32x4 v = *(const f32x4*)&y_sh[tq][obs][l16 * 4];
            float s = v[0] + v[1] + v[2] + v[3];
            s += __shfl_xor(s, 1); s += __shfl_xor(s, 2);
            s += __shfl_xor(s, 4); s += __shfl_xor(s, 8);
            float mean = s * (1.f / 64.f);
            float q = 0.f;
            #pragma unroll
            for (int j = 0; j < 4; ++j) { float d0 = v[j] - mean; q += d0 * d0; }
            q += __shfl_xor(q, 1); q += __shfl_xor(q, 2);
            q += __shfl_xor(q, 4); q += __shfl_xor(q, 8);
            float rstd = rsqrtf(q * (1.f / 64.f) + 1e-5f);
            const int row = ((o0 + obs) * 5 + tq) * 64;
            #pragma unroll
            for (int j = 0; j < 4; ++j) {
                int c = l16 * 4 + j;
                xo[row + c] = (v[j] - mean) * rstd * g1[c] + be1[c];
            }
        }
    }
}

// ---------------------------------------------------------------------------
// Fallback attention (pure VALU)
// ---------------------------------------------------------------------------
__global__ __launch_bounds__(NT) void k_att(
    float* __restrict__ x,
    const float* __restrict__ wqkv, const float* __restrict__ bqkv,
    const float* __restrict__ wo, const float* __restrict__ bo,
    const float* __restrict__ g1, const float* __restrict__ be1)
{
    const int b = blockIdx.x;
    const int tid = threadIdx.x;
    __shared__ float xs[5][64];
    __shared__ float qkv[5][192];
    __shared__ float att[4][5][5];
    __shared__ float os[5][64];
    __shared__ float xr[5][64];
    __shared__ float stat[5][2];

    for (int i = tid; i < 320; i += NT) xs[i >> 6][i & 63] = x[b * 320 + i];
    __syncthreads();

    for (int i = tid; i < 960; i += NT) {
        int p = i / 192, j = i % 192;
        float s = bqkv[j];
        const float* wr = wqkv + j * 64;
        const float* xm = xs[p];
        #pragma unroll
        for (int k = 0; k < 64; ++k) s += xm[k] * wr[k];
        qkv[p][j] = s;
    }
    __syncthreads();

    if (tid < 100) {
        int h = tid / 25, r = tid % 25, q = r / 5, kk = r % 5;
        float s = 0.f;
        #pragma unroll
        for (int d = 0; d < 16; ++d) s += qkv[q][h * 16 + d] * qkv[kk][64 + h * 16 + d];
        att[h][q][kk] = s * 0.25f;
    }
    __syncthreads();

    if (tid < 20) {
        int h = tid / 5, q = tid % 5;
        float m = att[h][q][0];
        for (int k = 1; k < 5; ++k) m = fmaxf(m, att[h][q][k]);
        float sum = 0.f;
        for (int k = 0; k < 5; ++k) { float e = expf(att[h][q][k] - m); att[h][q][k] = e; sum += e; }
        float inv = 1.f / sum;
        for (int k = 0; k < 5; ++k) att[h][q][k] *= inv;
    }
    __syncthreads();

    for (int i = tid; i < 320; i += NT) {
        int p = i >> 6, c = i & 63, h = c >> 4;
        float s = 0.f;
        #pragma unroll
        for (int k = 0; k < 5; ++k) s += att[h][p][k] * qkv[k][128 + c];
        os[p][c] = s;
    }
    __syncthreads();

    for (int i = tid; i < 320; i += NT) {
        int p = i >> 6, c = i & 63;
        float s = bo[c];
        const float* wr = wo + c * 64;
        const float* om = os[p];
        #pragma unroll
        for (int k = 0; k < 64; ++k) s += om[k] * wr[k];
        xr[p][c] = xs[p][c] + s;
    }
    __syncthreads();

    if (tid < 5) {
        float m = 0.f;
        for (int k = 0; k < 64; ++k) m += xr[tid][k];
        m *= (1.f / 64.f);
        float v = 0.f;
        for (int k = 0; k < 64; ++k) { float d = xr[tid][k] - m; v += d * d; }
        v *= (1.f / 64.f);
        stat[tid][0] = m;
        stat[tid][1] = 1.f / sqrtf(v + 1e-5f);
    }
    __syncthreads();

    for (int i = tid; i < 320; i += NT) {
        int p = i >> 6, c = i & 63;
        x[b * 320 + i] = (xr[p][c] - stat[p][0]) * stat[p][1] * g1[c] + be1[c];
    }
}

// ---------------------------------------------------------------------------
// Kernel 3 (MFMA, wave-split hidden, zero-barrier L2 streaming) - R11, proven
// ---------------------------------------------------------------------------
#define PKCH 8192
__global__ __launch_bounds__(256, 2) void k_ffn8(
    float* __restrict__ x,
    const unsigned short* __restrict__ wpk,
    const float* __restrict__ b1,
    const float* __restrict__ b2,
    const float* __restrict__ g2, const float* __restrict__ be2)
{
    __shared__ float red[4][4][4][64][4];
    const int tid  = threadIdx.x;
    const int lane = tid & 63;
    const int wid  = tid >> 6;
    const int lr = lane & 15;
    const int lg = lane >> 4;
    const int row0 = blockIdx.x * 64;

    bf16x8 bx[4][2];
    #pragma unroll
    for (int mf = 0; mf < 4; ++mf)
        #pragma unroll
        for (int kk = 0; kk < 2; ++kk) {
            const float* p = x + (row0 + mf * 16 + lr) * 64 + kk * 32 + lg * 8;
            f32x4 aa = *(const f32x4*)(p);
            f32x4 bb = *(const f32x4*)(p + 4);
            bx[mf][kk] = pk_bf16x8(aa, bb);
        }

    f32x4 acc[4][4] = {};
    const int fbase = (lg * 16 + lr) * 8;
    const unsigned short* wp = wpk + (wid * 8) * PKCH;
    const float* b1w = b1 + wid * 512;

    for (int c = 0; c < 8; ++c) {
        const unsigned short* L = wp + c * PKCH;
        bf16x8 rA[4], rB[4], rC[4], rD[4];
        #pragma unroll
        for (int hc = 0; hc < 4; ++hc) {
            rA[hc] = *(const bf16x8*)&L[hc * 512 + fbase];
            rB[hc] = *(const bf16x8*)&L[2048 + hc * 512 + fbase];
            rC[hc] = *(const bf16x8*)&L[4096 + hc * 512 + fbase];
            rD[hc] = *(const bf16x8*)&L[6144 + hc * 512 + fbase];
        }
        f32x4 b1v[4];
        #pragma unroll
        for (int hc = 0; hc < 4; ++hc)
            b1v[hc] = *(const f32x4*)(b1w + c * 64 + hc * 16 + lg * 4);

        #pragma unroll
        for (int hc = 0; hc < 4; ++hc) {
            #pragma unroll
            for (int mf = 0; mf < 4; ++mf) {
                f32x4 d = MFMA16x32(rA[hc], bx[mf][0], b1v[hc]);
                d = MFMA16x32(rB[hc], bx[mf][1], d);
                #pragma unroll
                for (int r = 0; r < 4; ++r) d[r] = fmaxf(d[r], 0.f);
                bf16x4 h = pk_bf16(d);
                acc[mf][0] = mfma16x16(h, lo4(rC[hc]), acc[mf][0]);
                acc[mf][1] = mfma16x16(h, hi4(rC[hc]), acc[mf][1]);
                acc[mf][2] = mfma16x16(h, lo4(rD[hc]), acc[mf][2]);
                acc[mf][3] = mfma16x16(h, hi4(rD[hc]), acc[mf][3]);
            }
        }
    }

    #pragma unroll
    for (int mf = 0; mf < 4; ++mf)
        #pragma unroll
        for (int nf = 0; nf < 4; ++nf)
            *(f32x4*)&red[wid][mf][nf][lane][0] = acc[mf][nf];
    __syncthreads();

    f32x4 vr[4];
    #pragma unroll
    for (int nf = 0; nf < 4; ++nf) {
        f32x4 s0 = *(const f32x4*)&red[0][wid][nf][lane][0];
        f32x4 s1 = *(const f32x4*)&red[1][wid][nf][lane][0];
        f32x4 s2 = *(const f32x4*)&red[2][wid][nf][lane][0];
        f32x4 s3 = *(const f32x4*)&red[3][wid][nf][lane][0];
        vr[nf] = (s0 + s1) + (s2 + s3);
    }

    #pragma unroll
    for (int r = 0; r < 4; ++r) {
        const int m = row0 + wid * 16 + lg * 4 + r;
        float v[4];
        float s = 0.f;
        #pragma unroll
        for (int nf = 0; nf < 4; ++nf) {
            int cc = nf * 16 + lr;
            float y = vr[nf][r] + b2[cc] + x[m * 64 + cc];
            v[nf] = y; s += y;
        }
        s += __shfl_xor(s, 1); s += __shfl_xor(s, 2);
        s += __shfl_xor(s, 4); s += __shfl_xor(s, 8);
        float mean = s * (1.f / 64.f);
        float q = 0.f;
        #pragma unroll
        for (int nf = 0; nf < 4; ++nf) { float d0 = v[nf] - mean; q += d0 * d0; }
        q += __shfl_xor(q, 1); q += __shfl_xor(q, 2);
        q += __shfl_xor(q, 4); q += __shfl_xor(q, 8);
        float rstd = rsqrtf(q * (1.f / 64.f) + 1e-5f);
        #pragma unroll
        for (int nf = 0; nf < 4; ++nf) {
            int cc = nf * 16 + lr;
            x[m * 64 + cc] = (v[nf] - mean) * rstd * g2[cc] + be2[cc];
        }
    }
}

// ---------------------------------------------------------------------------
// Fallback FFN (pure VALU)
// ---------------------------------------------------------------------------
#define GRP 8
#define ROWS (GRP * 5)
__global__ __launch_bounds__(NT) void k_ffn(
    float* __restrict__ x,
    const float* __restrict__ w1, const float* __restrict__ b1,
    const float* __restrict__ w2, const float* __restrict__ b2,
    const float* __restrict__ g2, const float* __restrict__ be2)
{
    const int tid = threadIdx.x;
    const int base = blockIdx.x * (ROWS * 64);
    __shared__ float xs[ROWS][64];
    __shared__ float hch[ROWS][128];
    __shared__ float stat[ROWS][2];

    for (int i = tid; i < ROWS * 64; i += NT) xs[i >> 6][i & 63] = x[base + i];
    __syncthreads();

    const int c = tid & 63;
    const int g = tid >> 6;
    float acc[10];
    #pragma unroll
    for (int r = 0; r < 10; ++r) acc[r] = 0.f;

    for (int ch = 0; ch < 16; ++ch) {
        for (int ii = tid; ii < ROWS * 128; ii += NT) {
            int m = ii >> 7, j = ii & 127;
            int jj = (ch << 7) + j;
            float s = b1[jj];
            const float* wr = w1 + jj * 64;
            const float* xm = xs[m];
            #pragma unroll
            for (int k = 0; k < 64; ++k) s += xm[k] * wr[k];
            hch[m][j] = fmaxf(s, 0.f);
        }
        __syncthreads();
        const float* w2r = w2 + c * 2048 + (ch << 7);
        for (int j = 0; j < 128; ++j) {
            float wv = w2r[j];
            #pragma unroll
            for (int r = 0; r < 10; ++r) acc[r] += hch[g * 10 + r][j] * wv;
        }
        __syncthreads();
    }

    #pragma unroll
    for (int r = 0; r < 10; ++r) {
        int m = g * 10 + r;
        hch[m][c] = acc[r] + b2[c] + xs[m][c];
    }
    __syncthreads();

    if (tid < ROWS) {
        float m = 0.f;
        for (int k = 0; k < 64; ++k) m += hch[tid][k];
        m *= (1.f / 64.f);
        float v = 0.f;
        for (int k = 0; k < 64; ++k) { float d = hch[tid][k] - m; v += d * d; }
        v *= (1.f / 64.f);
        stat[tid][0] = m;
        stat[tid][1] = 1.f / sqrtf(v + 1e-5f);
    }
    __syncthreads();

    for (int i = tid; i < ROWS * 64; i += NT) {
        int m = i >> 6, cc = i & 63;
        x[base + i] = (hch[m][cc] - stat[m][0]) * stat[m][1] * g2[cc] + be2[cc];
    }
}

// ---------------------------------------------------------------------------
extern "C" void kernel_launch(void* const* d_in, const int* in_sizes, int n_in,
                              void* d_out, int out_size, void* d_ws, size_t ws_size,
                              hipStream_t stream)
{
    (void)in_sizes; (void)n_in; (void)out_size;
    const int*   ai       = (const int*)d_in[0];
    const int*   aj       = (const int*)d_in[1];
    const int*   gi       = (const int*)d_in[2];
    const int*   gj       = (const int*)d_in[3];
    const int*   walls    = (const int*)d_in[4];
    const float* mlp_w1   = (const float*)d_in[5];
    const float* mlp_b1   = (const float*)d_in[6];
    const float* mlp_w2   = (const float*)d_in[7];
    const float* mlp_b2   = (const float*)d_in[8];
    const float* in_proj_w = (const float*)d_in[9];
    const float* in_proj_b = (const float*)d_in[10];
    const float* out_w    = (const float*)d_in[11];
    const float* out_b    = (const float*)d_in[12];
    const float* ln1_g    = (const float*)d_in[13];
    const float* ln1_b    = (const float*)d_in[14];
    const float* ln2_g    = (const float*)d_in[15];
    const float* ln2_b    = (const float*)d_in[16];
    const float* ffn_w1   = (const float*)d_in[17];
    const float* ffn_b1   = (const float*)d_in[18];
    const float* ffn_w2   = (const float*)d_in[19];
    const float* ffn_b2   = (const float*)d_in[20];

    float* x = (float*)d_out;
    const int B = 8192;
    const bool fast  = ws_size >= (size_t)(WS_BASE * 2);
    const bool fast2 = ws_size >= (size_t)(WS_TOTAL * 2);
    unsigned short* wsbf = (unsigned short*)d_ws;

    if (fast)
        k_cvtw<<<2048, NT, 0, stream>>>(ffn_w1, ffn_w2, in_proj_w, out_w,
                                        mlp_w1, mlp_w2, fast2 ? 1 : 0, wsbf);

    if (fast2) {
        k_feat2<<<B / FB, 320, 0, stream>>>(ai, aj, gi, gj, walls,
            wsbf + WS_MW1, mlp_b1, wsbf + WS_MW2, mlp_b2, x);
    } else {
        k_feat<<<B, NT, 0, stream>>>(ai, aj, gi, gj, walls,
                                     mlp_w1, mlp_b1, mlp_w2, mlp_b2, x);
    }

    for (int l = 0; l < 2; ++l) {
        if (fast) {
            k_att3<<<512, 256, 0, stream>>>(x, x,
                wsbf + WS_QKV + l * 12288, in_proj_b + l * 192,
                wsbf + WS_WO + l * 4096, out_b + l * 64,
                ln1_g + l * 64, ln1_b + l * 64);
            k_ffn8<<<640, 256, 0, stream>>>(x,
                wsbf + WS_FPK + l * 262144, ffn_b1 + l * 2048,
                ffn_b2 + l * 64,
                ln2_g + l * 64, ln2_b + l * 64);
        } else {
            k_att<<<B, NT, 0, stream>>>(x,
                in_proj_w + l * 192 * 64, in_proj_b + l * 192,
                out_w + l * 64 * 64, out_b + l * 64,
                ln1_g + l * 64, ln1_b + l * 64);
            k_ffn<<<B / GRP, NT, 0, stream>>>(x,
                ffn_w1 + l * 2048 * 64, ffn_b1 + l * 2048,
                ffn_w2 + l * 64 * 2048, ffn_b2 + l * 64,
                ln2_g + l * 64, ln2_b + l * 64);
        }
    }
}